// Round 1
// baseline (744.491 us; speedup 1.0000x reference)
//
#include <hip/hip_runtime.h>
#include <math.h>

#define E_DIM 512
#define NSEQ  2048
#define BATCH 2
#define NHEAD 8
#define HD    64

// ---------------------------------------------------------------------------
// Generic tiled fp32 matmul: out = X @ W^T + b with per-mode epilogue.
// X: [4096, 512] row-major. W: [512, 512] row-major (torch Linear weight).
// mode 0: Q -> rotary, store [B,H,N,D]
// mode 1: K -> rotary, *0.125, store [B,H,N,D]
// mode 2: V -> store [B,H,N,D]
// mode 3: G -> silu, store [B,N,E]
// mode 4: plain, store [B,N,E]  (output projection)
// Tile: BM=64 rows, BN=64 cols, BK=16. 256 threads, 4x4 microtile/thread.
// ---------------------------------------------------------------------------
__global__ __launch_bounds__(256) void proj_kernel(
    const float* __restrict__ X, const float* __restrict__ W,
    const float* __restrict__ bias, float* __restrict__ out, int mode)
{
    __shared__ float As[16][65];   // [BK][BM+1]
    __shared__ float Ws[64][17];   // [BN][BK+1]

    const int t  = threadIdx.x;
    const int tx = t & 15, ty = t >> 4;
    const int m0 = blockIdx.y * 64;
    const int n0 = blockIdx.x * 64;

    float acc[4][4] = {};

    for (int k0 = 0; k0 < E_DIM; k0 += 16) {
        #pragma unroll
        for (int i = 0; i < 4; ++i) {
            int idx = t + i * 256;
            int row = idx >> 4, col = idx & 15;
            As[col][row] = X[(m0 + row) * E_DIM + k0 + col];
        }
        #pragma unroll
        for (int i = 0; i < 4; ++i) {
            int idx = t + i * 256;
            int row = idx >> 4, col = idx & 15;
            Ws[row][col] = W[(n0 + row) * E_DIM + k0 + col];
        }
        __syncthreads();
        #pragma unroll
        for (int kk = 0; kk < 16; ++kk) {
            float a[4], w[4];
            #pragma unroll
            for (int i = 0; i < 4; ++i) a[i] = As[kk][ty * 4 + i];
            #pragma unroll
            for (int j = 0; j < 4; ++j) w[j] = Ws[tx * 4 + j][kk];
            #pragma unroll
            for (int i = 0; i < 4; ++i)
                #pragma unroll
                for (int j = 0; j < 4; ++j)
                    acc[i][j] += a[i] * w[j];
        }
        __syncthreads();
    }

    const int coln = n0 + tx * 4;
    float bv[4];
    #pragma unroll
    for (int j = 0; j < 4; ++j) bv[j] = bias[coln + j];

    #pragma unroll
    for (int i = 0; i < 4; ++i) {
        int r = m0 + ty * 4 + i;         // global row in [0, 4096)
        int bb = r >> 11;                // batch
        int n  = r & (NSEQ - 1);         // position

        if (mode == 0 || mode == 1) {
            #pragma unroll
            for (int jp = 0; jp < 2; ++jp) {
                int e0 = coln + jp * 2;      // even column
                int h  = e0 >> 6;
                int d0 = e0 & 63;
                int p  = d0 >> 1;            // pair index 0..31
                float theta = powf(10000.0f, -(float)p * (1.0f / 31.0f));
                float ang = (float)n * theta;
                float sv = sinf(ang), cv = cosf(ang);
                float x0 = acc[i][jp * 2]     + bv[jp * 2];
                float x1 = acc[i][jp * 2 + 1] + bv[jp * 2 + 1];
                float y0 = x0 * cv - x1 * sv;
                float y1 = x1 * cv + x0 * sv;
                if (mode == 1) { y0 *= 0.125f; y1 *= 0.125f; }
                long base = ((long)(bb * NHEAD + h) * NSEQ + n) * HD + d0;
                out[base]     = y0;
                out[base + 1] = y1;
            }
        } else if (mode == 2) {
            #pragma unroll
            for (int j = 0; j < 4; ++j) {
                int e = coln + j;
                out[((long)(bb * NHEAD + (e >> 6)) * NSEQ + n) * HD + (e & 63)] =
                    acc[i][j] + bv[j];
            }
        } else if (mode == 3) {
            #pragma unroll
            for (int j = 0; j < 4; ++j) {
                float x = acc[i][j] + bv[j];
                out[(long)r * E_DIM + coln + j] = x / (1.0f + expf(-x));
            }
        } else {
            #pragma unroll
            for (int j = 0; j < 4; ++j)
                out[(long)r * E_DIM + coln + j] = acc[i][j] + bv[j];
        }
    }
}

// ---------------------------------------------------------------------------
// Retention attention, flash-style. One block per (b,h,q-tile of 64 rows).
// S = Q Kt^T (K already scaled by 1/sqrt(D)), S *= gamma^(n-s) (causal),
// ret = S V, then per-row GroupNorm over D=64, multiply by gate, store to
// RG [B,N,E] fp32.
// ---------------------------------------------------------------------------
__global__ __launch_bounds__(256) void attn_kernel(
    const float* __restrict__ Q, const float* __restrict__ K,
    const float* __restrict__ V, const float* __restrict__ G,
    float* __restrict__ RG)
{
    __shared__ float Qs[64][65];
    __shared__ float KVs[64][65];
    __shared__ float Ps[64][65];
    __shared__ float rowm[64], rowr[64];

    const int t  = threadIdx.x;
    const int tx = t & 15, ty = t >> 4;
    const int bh = blockIdx.y;          // b*8 + h
    const int h  = bh & 7;
    const int b  = bh >> 3;
    const int qt = blockIdx.x;
    const int n0 = qt * 64;
    const long base = (long)bh * NSEQ * HD;

    // gamma for this head (match jnp.linspace in fp32-ish)
    float lg0 = logf(1.0f / 32.0f), lg1 = logf(1.0f / 512.0f);
    float gamma = 1.0f - expf(lg0 + (float)h * (lg1 - lg0) * (1.0f / 7.0f));
    float l2g = log2f(gamma);

    // load Q tile
    #pragma unroll
    for (int i = 0; i < 16; ++i) {
        int idx = t + i * 256;
        int row = idx >> 6, col = idx & 63;
        Qs[row][col] = Q[base + (long)(n0 + row) * HD + col];
    }

    float racc[4][4] = {};

    for (int st = 0; st <= qt; ++st) {
        const int s0 = st * 64;
        __syncthreads();   // previous iter's V reads done
        #pragma unroll
        for (int i = 0; i < 16; ++i) {
            int idx = t + i * 256;
            int row = idx >> 6, col = idx & 63;
            KVs[row][col] = K[base + (long)(s0 + row) * HD + col];
        }
        __syncthreads();

        // S tile: rows m=ty*4+i, cols s=tx*4+j
        float sacc[4][4] = {};
        for (int dd = 0; dd < HD; ++dd) {
            float qv[4], kv[4];
            #pragma unroll
            for (int i = 0; i < 4; ++i) qv[i] = Qs[ty * 4 + i][dd];
            #pragma unroll
            for (int j = 0; j < 4; ++j) kv[j] = KVs[tx * 4 + j][dd];
            #pragma unroll
            for (int i = 0; i < 4; ++i)
                #pragma unroll
                for (int j = 0; j < 4; ++j)
                    sacc[i][j] += qv[i] * kv[j];
        }
        // decay mask
        #pragma unroll
        for (int i = 0; i < 4; ++i) {
            int n = n0 + ty * 4 + i;
            #pragma unroll
            for (int j = 0; j < 4; ++j) {
                int s = s0 + tx * 4 + j;
                float w = (n >= s) ? exp2f((float)(n - s) * l2g) : 0.0f;
                Ps[ty * 4 + i][tx * 4 + j] = sacc[i][j] * w;
            }
        }
        __syncthreads();   // Ps ready AND everyone done reading K

        #pragma unroll
        for (int i = 0; i < 16; ++i) {
            int idx = t + i * 256;
            int row = idx >> 6, col = idx & 63;
            KVs[row][col] = V[base + (long)(s0 + row) * HD + col];
        }
        __syncthreads();

        // ret += P @ V : rows m=ty*4+i, cols d=tx*4+j
        for (int ss = 0; ss < 64; ++ss) {
            float pv[4], vv[4];
            #pragma unroll
            for (int i = 0; i < 4; ++i) pv[i] = Ps[ty * 4 + i][ss];
            #pragma unroll
            for (int j = 0; j < 4; ++j) vv[j] = KVs[ss][tx * 4 + j];
            #pragma unroll
            for (int i = 0; i < 4; ++i)
                #pragma unroll
                for (int j = 0; j < 4; ++j)
                    racc[i][j] += pv[i] * vv[j];
        }
    }

    // GroupNorm per row over D=64, then gate, then store
    __syncthreads();
    #pragma unroll
    for (int i = 0; i < 4; ++i)
        #pragma unroll
        for (int j = 0; j < 4; ++j)
            Ps[ty * 4 + i][tx * 4 + j] = racc[i][j];
    __syncthreads();

    if (t < 64) {
        float sum = 0.0f;
        #pragma unroll
        for (int x = 0; x < 64; ++x) sum += Ps[t][x];
        float mean = sum * (1.0f / 64.0f);
        float vs = 0.0f;
        #pragma unroll
        for (int x = 0; x < 64; ++x) {
            float dvd = Ps[t][x] - mean;
            vs += dvd * dvd;
        }
        rowm[t] = mean;
        rowr[t] = rsqrtf(vs * (1.0f / 64.0f) + 1e-6f);
    }
    __syncthreads();

    #pragma unroll
    for (int i = 0; i < 4; ++i) {
        int m = ty * 4 + i;
        int n = n0 + m;
        float mean = rowm[m], rstd = rowr[m];
        #pragma unroll
        for (int j = 0; j < 4; ++j) {
            int d = tx * 4 + j;
            float val = (racc[i][j] - mean) * rstd;
            long gi = ((long)(b * NSEQ + n)) * E_DIM + h * HD + d;
            RG[gi] = val * G[gi];
        }
    }
}

extern "C" void kernel_launch(void* const* d_in, const int* in_sizes, int n_in,
                              void* d_out, int out_size, void* d_ws, size_t ws_size,
                              hipStream_t stream) {
    const float* query = (const float*)d_in[0];
    const float* kin   = (const float*)d_in[1];
    const float* vin   = (const float*)d_in[2];
    const float* Wq = (const float*)d_in[3];
    const float* bq = (const float*)d_in[4];
    const float* Wk = (const float*)d_in[5];
    const float* bk = (const float*)d_in[6];
    const float* Wv = (const float*)d_in[7];
    const float* bv = (const float*)d_in[8];
    const float* Wg = (const float*)d_in[9];
    const float* bg = (const float*)d_in[10];
    const float* Wo = (const float*)d_in[11];
    const float* bo = (const float*)d_in[12];

    float* ws = (float*)d_ws;
    const long NTOK = (long)BATCH * NSEQ;            // 4096
    const long PER  = NTOK * E_DIM;                  // 2,097,152
    float* Qb = ws;
    float* Kb = ws + PER;
    float* Vb = ws + 2 * PER;
    float* Gb = ws + 3 * PER;
    float* RG = ws + 4 * PER;

    dim3 grid(E_DIM / 64, NTOK / 64);   // (8, 64)
    proj_kernel<<<grid, 256, 0, stream>>>(query, Wq, bq, Qb, 0);
    proj_kernel<<<grid, 256, 0, stream>>>(kin,   Wk, bk, Kb, 1);
    proj_kernel<<<grid, 256, 0, stream>>>(vin,   Wv, bv, Vb, 2);
    proj_kernel<<<grid, 256, 0, stream>>>(query, Wg, bg, Gb, 3);

    attn_kernel<<<dim3(NSEQ / 64, BATCH * NHEAD), 256, 0, stream>>>(Qb, Kb, Vb, Gb, RG);

    proj_kernel<<<grid, 256, 0, stream>>>(RG, Wo, bo, (float*)d_out, 4);
}

// Round 3
// 563.346 us; speedup vs baseline: 1.3216x; 1.3216x over previous
//
#include <hip/hip_runtime.h>
#include <math.h>

#define E_DIM 512
#define NSEQ  2048
#define BATCH 2
#define NHEAD 8
#define HD    64

typedef float f32x4 __attribute__((ext_vector_type(4)));
typedef short s16x8 __attribute__((ext_vector_type(8)));
typedef short s16x4 __attribute__((ext_vector_type(4)));

__device__ __forceinline__ short f2bf(float f) {
    unsigned u = __builtin_bit_cast(unsigned, f);
    unsigned r = u + 0x7FFFu + ((u >> 16) & 1u);
    return (short)(r >> 16);
}
__device__ __forceinline__ float bf2f(short h) {
    return __builtin_bit_cast(float, ((unsigned)(unsigned short)h) << 16);
}

// load 16 contiguous fp32, split into hi/lo bf16, store to LDS (16-short rows)
__device__ __forceinline__ void split16(const float* __restrict__ p,
                                        short* hi, short* lo) {
    f32x4 a0 = *(const f32x4*)(p);
    f32x4 a1 = *(const f32x4*)(p + 4);
    f32x4 a2 = *(const f32x4*)(p + 8);
    f32x4 a3 = *(const f32x4*)(p + 12);
    s16x8 h0, h1, l0, l1;
    #pragma unroll
    for (int i = 0; i < 4; ++i) {
        short h;
        h = f2bf(a0[i]); h0[i]     = h; l0[i]     = f2bf(a0[i] - bf2f(h));
        h = f2bf(a1[i]); h0[4 + i] = h; l0[4 + i] = f2bf(a1[i] - bf2f(h));
        h = f2bf(a2[i]); h1[i]     = h; l1[i]     = f2bf(a2[i] - bf2f(h));
        h = f2bf(a3[i]); h1[4 + i] = h; l1[4 + i] = f2bf(a3[i] - bf2f(h));
    }
    *(s16x8*)hi       = h0;
    *(s16x8*)(hi + 8) = h1;
    *(s16x8*)lo       = l0;
    *(s16x8*)(lo + 8) = l1;
}

// ---------------------------------------------------------------------------
// Split-bf16 MFMA GEMM: out = X @ W^T + b  (~fp32 accurate).
// X [4096,512] fp32, W [512,512] fp32. 128x128 tile, 4 waves 2x2, BK=32.
// mode 0: Q rotary -> [B,H,N,D]   mode 1: K rotary*0.125 -> [B,H,N,D]
// mode 2: V -> transposed [B,H,D,N]   mode 3: silu -> [B,N,E]   mode 4: plain
// ---------------------------------------------------------------------------
__global__ __launch_bounds__(256) void proj_kernel(
    const float* __restrict__ X, const float* __restrict__ W,
    const float* __restrict__ bias, float* __restrict__ out, int mode)
{
    __shared__ short Xh[128 * 40], Xl[128 * 40];
    __shared__ short Wh[128 * 40], Wl[128 * 40];

    const int t = threadIdx.x;
    const int lane = t & 63;
    const int wv = t >> 6;
    const int wm = wv >> 1, wn = wv & 1;
    const int quad = lane >> 4, l15 = lane & 15;
    const int m0 = blockIdx.y * 128, n0 = blockIdx.x * 128;

    f32x4 acc[4][4];
    #pragma unroll
    for (int i = 0; i < 4; ++i)
        #pragma unroll
        for (int j = 0; j < 4; ++j)
            acc[i][j] = (f32x4){0.f, 0.f, 0.f, 0.f};

    const int srow = t >> 1;
    const int scol = (t & 1) * 16;

    for (int k0 = 0; k0 < 512; k0 += 32) {
        __syncthreads();
        split16(X + (long)(m0 + srow) * 512 + k0 + scol,
                &Xh[srow * 40 + scol], &Xl[srow * 40 + scol]);
        split16(W + (long)(n0 + srow) * 512 + k0 + scol,
                &Wh[srow * 40 + scol], &Wl[srow * 40 + scol]);
        __syncthreads();

        s16x8 ah[4], al[4], bh[4], bl[4];
        #pragma unroll
        for (int s = 0; s < 4; ++s) {
            const int ro = (wm * 64 + s * 16 + l15) * 40 + quad * 8;
            ah[s] = *(const s16x8*)&Xh[ro];
            al[s] = *(const s16x8*)&Xl[ro];
        }
        #pragma unroll
        for (int s = 0; s < 4; ++s) {
            const int ro = (wn * 64 + s * 16 + l15) * 40 + quad * 8;
            bh[s] = *(const s16x8*)&Wh[ro];
            bl[s] = *(const s16x8*)&Wl[ro];
        }
        #pragma unroll
        for (int i = 0; i < 4; ++i)
            #pragma unroll
            for (int j = 0; j < 4; ++j) {
                acc[i][j] = __builtin_amdgcn_mfma_f32_16x16x32_bf16(ah[i], bh[j], acc[i][j], 0, 0, 0);
                acc[i][j] = __builtin_amdgcn_mfma_f32_16x16x32_bf16(al[i], bh[j], acc[i][j], 0, 0, 0);
                acc[i][j] = __builtin_amdgcn_mfma_f32_16x16x32_bf16(ah[i], bl[j], acc[i][j], 0, 0, 0);
            }
    }

    // epilogue
    #pragma unroll
    for (int ns = 0; ns < 4; ++ns) {
        const int col = n0 + wn * 64 + ns * 16 + l15;
        const float bv = bias[col];
        float theta = 0.f;
        if (mode <= 1) {
            int p = (col & 63) >> 1;
            theta = powf(10000.0f, -(float)p * (1.0f / 31.0f));
        }
        #pragma unroll
        for (int ms = 0; ms < 4; ++ms) {
            #pragma unroll
            for (int r = 0; r < 4; ++r) {
                const int m = m0 + wm * 64 + ms * 16 + quad * 4 + r;
                const int pos = m & 2047, bb = m >> 11;
                float x = acc[ms][ns][r] + bv;
                if (mode <= 1) {
                    float ang = (float)pos * theta;
                    float sv = sinf(ang), cv = cosf(ang);
                    float partner = __shfl_xor(x, 1);
                    float y = x * cv + ((col & 1) ? partner : -partner) * sv;
                    if (mode == 1) y *= 0.125f;
                    out[((long)(bb * 8 + (col >> 6)) * 2048 + pos) * 64 + (col & 63)] = y;
                } else if (mode == 2) {
                    out[((long)(bb * 8 + (col >> 6)) * 64 + (col & 63)) * 2048 + pos] = x;
                } else if (mode == 3) {
                    out[(long)m * 512 + col] = x / (1.0f + expf(-x));
                } else {
                    out[(long)m * 512 + col] = x;
                }
            }
        }
    }
}

// ---------------------------------------------------------------------------
// Retention attention, split-bf16 MFMA throughout (~fp32 accurate).
// Block = 4 waves; wave w owns q-rows n0+w*16..+15.
// S^T = K·Q^T (C-frag: 4 consecutive s per lane -> pack into P[n][s], which
// is wave-private so no barrier), then ret += P·V with Vt rows as B-frags.
// Fused GroupNorm (shuffle reduce) + gate.
// ---------------------------------------------------------------------------
__global__ __launch_bounds__(256) void attn_kernel(
    const float* __restrict__ Q, const float* __restrict__ K,
    const float* __restrict__ Vt, const float* __restrict__ G,
    float* __restrict__ RG)
{
    __shared__ short Qh[64 * 72], Ql[64 * 72];
    __shared__ short Kh[64 * 72], Kl[64 * 72];
    __shared__ short Vh[64 * 72], Vl[64 * 72];
    __shared__ short Ph[64 * 72], Pl[64 * 72];

    const int t = threadIdx.x, lane = t & 63, wv = t >> 6;
    const int quad = lane >> 4, l15 = lane & 15;
    const int bh = blockIdx.y, h = bh & 7, b = bh >> 3;
    const int qt = gridDim.x - 1 - blockIdx.x;   // big tiles launch first
    const int n0 = qt * 64;
    const long base = (long)bh * 2048 * 64;

    float l2g;
    {
        float lg0 = logf(1.0f / 32.0f), lg1 = logf(1.0f / 512.0f);
        float gamma = 1.0f - expf(lg0 + (float)h * (lg1 - lg0) * (1.0f / 7.0f));
        l2g = log2f(gamma);
    }

    const int srow = t >> 2;
    const int scol = (t & 3) * 16;

    // stage Q tile (fp32 -> hi/lo bf16)
    split16(Q + base + (long)(n0 + srow) * 64 + scol,
            &Qh[srow * 72 + scol], &Ql[srow * 72 + scol]);
    __syncthreads();
    s16x8 qh[2], ql[2];
    qh[0] = *(const s16x8*)&Qh[(wv * 16 + l15) * 72 + quad * 8];
    qh[1] = *(const s16x8*)&Qh[(wv * 16 + l15) * 72 + quad * 8 + 32];
    ql[0] = *(const s16x8*)&Ql[(wv * 16 + l15) * 72 + quad * 8];
    ql[1] = *(const s16x8*)&Ql[(wv * 16 + l15) * 72 + quad * 8 + 32];

    f32x4 racc[4];
    #pragma unroll
    for (int i = 0; i < 4; ++i) racc[i] = (f32x4){0.f, 0.f, 0.f, 0.f};

    for (int st = 0; st <= qt; ++st) {
        const int s0 = st * 64;
        __syncthreads();   // previous iteration's Kh/Kl/Vh/Vl reads done
        split16(K + base + (long)(s0 + srow) * 64 + scol,
                &Kh[srow * 72 + scol], &Kl[srow * 72 + scol]);
        split16(Vt + base + (long)srow * 2048 + s0 + scol,
                &Vh[srow * 72 + scol], &Vl[srow * 72 + scol]);
        __syncthreads();

        // S^T = K · Q^T, 16x16 s-subtiles; split product (KhQh + KlQh + KhQl)
        #pragma unroll
        for (int sub = 0; sub < 4; ++sub) {
            const int ro = (sub * 16 + l15) * 72 + quad * 8;
            s16x8 kh0 = *(const s16x8*)&Kh[ro];
            s16x8 kh1 = *(const s16x8*)&Kh[ro + 32];
            s16x8 kl0 = *(const s16x8*)&Kl[ro];
            s16x8 kl1 = *(const s16x8*)&Kl[ro + 32];
            f32x4 sacc = (f32x4){0.f, 0.f, 0.f, 0.f};
            sacc = __builtin_amdgcn_mfma_f32_16x16x32_bf16(kh0, qh[0], sacc, 0, 0, 0);
            sacc = __builtin_amdgcn_mfma_f32_16x16x32_bf16(kh1, qh[1], sacc, 0, 0, 0);
            sacc = __builtin_amdgcn_mfma_f32_16x16x32_bf16(kl0, qh[0], sacc, 0, 0, 0);
            sacc = __builtin_amdgcn_mfma_f32_16x16x32_bf16(kl1, qh[1], sacc, 0, 0, 0);
            sacc = __builtin_amdgcn_mfma_f32_16x16x32_bf16(kh0, ql[0], sacc, 0, 0, 0);
            sacc = __builtin_amdgcn_mfma_f32_16x16x32_bf16(kh1, ql[1], sacc, 0, 0, 0);

            const int n = n0 + wv * 16 + l15;
            const int sb = s0 + sub * 16 + quad * 4;
            s16x4 pkh, pkl;
            #pragma unroll
            for (int r = 0; r < 4; ++r) {
                const int s = sb + r;
                const float wgt = (n >= s) ? exp2f((float)(n - s) * l2g) : 0.0f;
                const float p = sacc[r] * wgt;
                short hb = f2bf(p);
                pkh[r] = hb;
                pkl[r] = f2bf(p - bf2f(hb));
            }
            const int po = (wv * 16 + l15) * 72 + sub * 16 + quad * 4;
            *(s16x4*)&Ph[po] = pkh;
            *(s16x4*)&Pl[po] = pkl;
        }

        // ret += P · V  (wave-private P rows; compiler's lgkmcnt covers RAW)
        const int pro = (wv * 16 + l15) * 72 + quad * 8;
        s16x8 ph0 = *(const s16x8*)&Ph[pro];
        s16x8 ph1 = *(const s16x8*)&Ph[pro + 32];
        s16x8 pl0 = *(const s16x8*)&Pl[pro];
        s16x8 pl1 = *(const s16x8*)&Pl[pro + 32];
        #pragma unroll
        for (int ds = 0; ds < 4; ++ds) {
            const int ro = (ds * 16 + l15) * 72 + quad * 8;
            s16x8 vh0 = *(const s16x8*)&Vh[ro];
            s16x8 vh1 = *(const s16x8*)&Vh[ro + 32];
            s16x8 vl0 = *(const s16x8*)&Vl[ro];
            s16x8 vl1 = *(const s16x8*)&Vl[ro + 32];
            racc[ds] = __builtin_amdgcn_mfma_f32_16x16x32_bf16(ph0, vh0, racc[ds], 0, 0, 0);
            racc[ds] = __builtin_amdgcn_mfma_f32_16x16x32_bf16(ph1, vh1, racc[ds], 0, 0, 0);
            racc[ds] = __builtin_amdgcn_mfma_f32_16x16x32_bf16(pl0, vh0, racc[ds], 0, 0, 0);
            racc[ds] = __builtin_amdgcn_mfma_f32_16x16x32_bf16(pl1, vh1, racc[ds], 0, 0, 0);
            racc[ds] = __builtin_amdgcn_mfma_f32_16x16x32_bf16(ph0, vl0, racc[ds], 0, 0, 0);
            racc[ds] = __builtin_amdgcn_mfma_f32_16x16x32_bf16(ph1, vl1, racc[ds], 0, 0, 0);
        }
    }

    // GroupNorm over d (64) per q-row, then gate, store fp32
    float mean[4], rstd[4];
    #pragma unroll
    for (int r = 0; r < 4; ++r) {
        float s = racc[0][r] + racc[1][r] + racc[2][r] + racc[3][r];
        s += __shfl_xor(s, 1); s += __shfl_xor(s, 2);
        s += __shfl_xor(s, 4); s += __shfl_xor(s, 8);
        mean[r] = s * (1.0f / 64.0f);
        float vs = 0.f;
        #pragma unroll
        for (int ds = 0; ds < 4; ++ds) {
            float d = racc[ds][r] - mean[r];
            vs += d * d;
        }
        vs += __shfl_xor(vs, 1); vs += __shfl_xor(vs, 2);
        vs += __shfl_xor(vs, 4); vs += __shfl_xor(vs, 8);
        rstd[r] = rsqrtf(vs * (1.0f / 64.0f) + 1e-6f);
    }
    #pragma unroll
    for (int ds = 0; ds < 4; ++ds) {
        #pragma unroll
        for (int r = 0; r < 4; ++r) {
            const int n = n0 + wv * 16 + quad * 4 + r;
            const int d = ds * 16 + l15;
            const long gi = ((long)(b * 2048 + n)) * 512 + h * 64 + d;
            RG[gi] = (racc[ds][r] - mean[r]) * rstd[r] * G[gi];
        }
    }
}

extern "C" void kernel_launch(void* const* d_in, const int* in_sizes, int n_in,
                              void* d_out, int out_size, void* d_ws, size_t ws_size,
                              hipStream_t stream) {
    const float* query = (const float*)d_in[0];
    const float* kin   = (const float*)d_in[1];
    const float* vin   = (const float*)d_in[2];
    const float* Wq = (const float*)d_in[3];
    const float* bq = (const float*)d_in[4];
    const float* Wk = (const float*)d_in[5];
    const float* bk = (const float*)d_in[6];
    const float* Wv = (const float*)d_in[7];
    const float* bv = (const float*)d_in[8];
    const float* Wg = (const float*)d_in[9];
    const float* bg = (const float*)d_in[10];
    const float* Wo = (const float*)d_in[11];
    const float* bo = (const float*)d_in[12];

    float* ws = (float*)d_ws;
    const long PER = 4096L * 512;
    float* Qb  = ws;
    float* Kb  = ws + PER;
    float* Vtb = ws + 2 * PER;
    float* Gb  = ws + 3 * PER;
    float* RG  = ws + 4 * PER;

    dim3 grid(4, 32);
    proj_kernel<<<grid, 256, 0, stream>>>(query, Wq, bq, Qb, 0);
    proj_kernel<<<grid, 256, 0, stream>>>(kin,   Wk, bk, Kb, 1);
    proj_kernel<<<grid, 256, 0, stream>>>(vin,   Wv, bv, Vtb, 2);
    proj_kernel<<<grid, 256, 0, stream>>>(query, Wg, bg, Gb, 3);

    attn_kernel<<<dim3(32, 16), 256, 0, stream>>>(Qb, Kb, Vtb, Gb, RG);

    proj_kernel<<<grid, 256, 0, stream>>>(RG, Wo, bo, (float*)d_out, 4);
}

// Round 4
// 333.091 us; speedup vs baseline: 2.2351x; 1.6913x over previous
//
#include <hip/hip_runtime.h>
#include <math.h>

typedef float f32x4 __attribute__((ext_vector_type(4)));
typedef short s16x8 __attribute__((ext_vector_type(8)));
typedef short s16x4 __attribute__((ext_vector_type(4)));

__device__ __forceinline__ short f2bf(float f) {
    unsigned u = __builtin_bit_cast(unsigned, f);
    unsigned r = u + 0x7FFFu + ((u >> 16) & 1u);
    return (short)(r >> 16);
}
__device__ __forceinline__ float bf2f(short h) {
    return __builtin_bit_cast(float, ((unsigned)(unsigned short)h) << 16);
}

// split 16 contiguous fp32 at p into hi/lo bf16 pairs at hi[0..15], lo[0..15]
__device__ __forceinline__ void split16(const float* __restrict__ p,
                                        short* hi, short* lo) {
    f32x4 a0 = *(const f32x4*)(p);
    f32x4 a1 = *(const f32x4*)(p + 4);
    f32x4 a2 = *(const f32x4*)(p + 8);
    f32x4 a3 = *(const f32x4*)(p + 12);
    s16x8 h0, h1, l0, l1;
    #pragma unroll
    for (int i = 0; i < 4; ++i) {
        short h;
        h = f2bf(a0[i]); h0[i]     = h; l0[i]     = f2bf(a0[i] - bf2f(h));
        h = f2bf(a1[i]); h0[4 + i] = h; l0[4 + i] = f2bf(a1[i] - bf2f(h));
        h = f2bf(a2[i]); h1[i]     = h; l1[i]     = f2bf(a2[i] - bf2f(h));
        h = f2bf(a3[i]); h1[4 + i] = h; l1[4 + i] = f2bf(a3[i] - bf2f(h));
    }
    *(s16x8*)hi       = h0;
    *(s16x8*)(hi + 8) = h1;
    *(s16x8*)lo       = l0;
    *(s16x8*)(lo + 8) = l1;
}

// ---------------------------------------------------------------------------
// Pre-split the 5 weight matrices (512x512 fp32 each) into hi/lo bf16.
// Layout at outbase: w*524288 + (hi: 0..262143, lo: 262144..)
// ---------------------------------------------------------------------------
__global__ __launch_bounds__(256) void wsplit_kernel(
    const float* __restrict__ W0, const float* __restrict__ W1,
    const float* __restrict__ W2, const float* __restrict__ W3,
    const float* __restrict__ W4, short* __restrict__ outbase)
{
    const int blk = blockIdx.x;          // 0..319, 64 blocks per W
    const int w = blk >> 6;
    const int bi = blk & 63;
    const float* src = (w == 0) ? W0 : (w == 1) ? W1 : (w == 2) ? W2
                      : (w == 3) ? W3 : W4;
    short* hi = outbase + (long)w * 524288;
    short* lo = hi + 262144;
    const int idx = (bi * 256 + threadIdx.x) * 16;
    split16(src + idx, hi + idx, lo + idx);
}

// ---------------------------------------------------------------------------
// Fused Q/K/V/G projections. blockIdx.z = mode.
// X fp32 (split in-kernel), W pre-split bf16. 128x128 tile, 4 waves 2x2, BK=32.
// mode 0: Q rotary -> split [B,H,N,D]; 1: K rotary*0.125 -> split [B,H,N,D];
// mode 2: V -> split [B,H,N,D] (transposed later); 3: G silu -> fp32 [B,N,E]
// ---------------------------------------------------------------------------
__global__ __launch_bounds__(256) void projqkvg_kernel(
    const float* __restrict__ Xq, const float* __restrict__ Xk,
    const float* __restrict__ Xv, const short* __restrict__ Wsp,
    const float* __restrict__ bq, const float* __restrict__ bk,
    const float* __restrict__ bv, const float* __restrict__ bg,
    short* __restrict__ Qh, short* __restrict__ Ql,
    short* __restrict__ Kh, short* __restrict__ Kl,
    short* __restrict__ V0h, short* __restrict__ V0l,
    float* __restrict__ G)
{
    __shared__ short XhS[128 * 40], XlS[128 * 40];
    __shared__ short WhS[128 * 40], WlS[128 * 40];

    const int mode = blockIdx.z;
    const float* X = (mode == 1) ? Xk : (mode == 2) ? Xv : Xq;
    const short* Wh_g = Wsp + (long)mode * 524288;
    const short* Wl_g = Wh_g + 262144;
    const float* bias = (mode == 0) ? bq : (mode == 1) ? bk
                       : (mode == 2) ? bv : bg;

    const int t = threadIdx.x;
    const int lane = t & 63;
    const int wv = t >> 6;
    const int wm = wv >> 1, wn = wv & 1;
    const int quad = lane >> 4, l15 = lane & 15;
    const int m0 = blockIdx.y * 128, n0 = blockIdx.x * 128;

    f32x4 acc[4][4];
    #pragma unroll
    for (int i = 0; i < 4; ++i)
        #pragma unroll
        for (int j = 0; j < 4; ++j)
            acc[i][j] = (f32x4){0.f, 0.f, 0.f, 0.f};

    const int srow = t >> 1;
    const int scol = (t & 1) * 16;

    for (int k0 = 0; k0 < 512; k0 += 32) {
        __syncthreads();
        split16(X + (long)(m0 + srow) * 512 + k0 + scol,
                &XhS[srow * 40 + scol], &XlS[srow * 40 + scol]);
        {
            const long wo = (long)(n0 + srow) * 512 + k0 + scol;
            s16x8 w0 = *(const s16x8*)(Wh_g + wo);
            s16x8 w1 = *(const s16x8*)(Wh_g + wo + 8);
            s16x8 w2 = *(const s16x8*)(Wl_g + wo);
            s16x8 w3 = *(const s16x8*)(Wl_g + wo + 8);
            *(s16x8*)&WhS[srow * 40 + scol]     = w0;
            *(s16x8*)&WhS[srow * 40 + scol + 8] = w1;
            *(s16x8*)&WlS[srow * 40 + scol]     = w2;
            *(s16x8*)&WlS[srow * 40 + scol + 8] = w3;
        }
        __syncthreads();

        s16x8 ah[4], al[4], bh[4], bl[4];
        #pragma unroll
        for (int s = 0; s < 4; ++s) {
            const int ro = (wm * 64 + s * 16 + l15) * 40 + quad * 8;
            ah[s] = *(const s16x8*)&XhS[ro];
            al[s] = *(const s16x8*)&XlS[ro];
        }
        #pragma unroll
        for (int s = 0; s < 4; ++s) {
            const int ro = (wn * 64 + s * 16 + l15) * 40 + quad * 8;
            bh[s] = *(const s16x8*)&WhS[ro];
            bl[s] = *(const s16x8*)&WlS[ro];
        }
        #pragma unroll
        for (int i = 0; i < 4; ++i)
            #pragma unroll
            for (int j = 0; j < 4; ++j) {
                acc[i][j] = __builtin_amdgcn_mfma_f32_16x16x32_bf16(ah[i], bh[j], acc[i][j], 0, 0, 0);
                acc[i][j] = __builtin_amdgcn_mfma_f32_16x16x32_bf16(al[i], bh[j], acc[i][j], 0, 0, 0);
                acc[i][j] = __builtin_amdgcn_mfma_f32_16x16x32_bf16(ah[i], bl[j], acc[i][j], 0, 0, 0);
            }
    }

    short* OH = (mode == 0) ? Qh : (mode == 1) ? Kh : V0h;
    short* OL = (mode == 0) ? Ql : (mode == 1) ? Kl : V0l;

    #pragma unroll
    for (int ns = 0; ns < 4; ++ns) {
        const int col = n0 + wn * 64 + ns * 16 + l15;
        const float bvv = bias[col];
        float theta = 0.f;
        if (mode <= 1) {
            int p = (col & 63) >> 1;
            theta = powf(10000.0f, -(float)p * (1.0f / 31.0f));
        }
        #pragma unroll
        for (int ms = 0; ms < 4; ++ms) {
            #pragma unroll
            for (int r = 0; r < 4; ++r) {
                const int m = m0 + wm * 64 + ms * 16 + quad * 4 + r;
                const int pos = m & 2047, bb = m >> 11;
                float x = acc[ms][ns][r] + bvv;
                if (mode <= 1) {
                    float ang = (float)pos * theta;
                    float sv = sinf(ang), cv = cosf(ang);
                    float partner = __shfl_xor(x, 1);
                    float y = x * cv + ((col & 1) ? partner : -partner) * sv;
                    if (mode == 1) y *= 0.125f;
                    const long o = ((long)(bb * 8 + (col >> 6)) * 2048 + pos) * 64 + (col & 63);
                    short hb = f2bf(y);
                    OH[o] = hb;
                    OL[o] = f2bf(y - bf2f(hb));
                } else if (mode == 2) {
                    const long o = ((long)(bb * 8 + (col >> 6)) * 2048 + pos) * 64 + (col & 63);
                    short hb = f2bf(x);
                    OH[o] = hb;
                    OL[o] = f2bf(x - bf2f(hb));
                } else {
                    G[(long)m * 512 + col] = x / (1.0f + expf(-x));
                }
            }
        }
    }
}

// ---------------------------------------------------------------------------
// Transpose V [B,H,N,D] -> Vt [B,H,D,N] (hi and lo bf16), coalesced via LDS.
// ---------------------------------------------------------------------------
__global__ __launch_bounds__(256) void vtrans_kernel(
    const short* __restrict__ Vh, const short* __restrict__ Vl,
    short* __restrict__ Vth, short* __restrict__ Vtl)
{
    __shared__ short T[64][72];
    const int t = threadIdx.x;
    const int bh = blockIdx.y;
    const int n0 = blockIdx.x * 64;
    const long ib = (long)bh * 2048 * 64;

    #pragma unroll
    for (int p = 0; p < 2; ++p) {
        const short* src = p ? Vl : Vh;
        short* dst = p ? Vtl : Vth;
        __syncthreads();
        {
            const int row = t >> 2, c0 = (t & 3) * 16;
            const long o = ib + (long)(n0 + row) * 64 + c0;
            s16x8 a = *(const s16x8*)(src + o);
            s16x8 b = *(const s16x8*)(src + o + 8);
            *(s16x8*)&T[row][c0] = a;
            *(s16x8*)&T[row][c0 + 8] = b;
        }
        __syncthreads();
        {
            const int d = t >> 2, n1 = (t & 3) * 16;
            s16x8 o0, o1;
            #pragma unroll
            for (int j = 0; j < 8; ++j) {
                o0[j] = T[n1 + j][d];
                o1[j] = T[n1 + 8 + j][d];
            }
            const long o = ib + (long)d * 2048 + n0 + n1;
            *(s16x8*)(dst + o) = o0;
            *(s16x8*)(dst + o + 8) = o1;
        }
    }
}

// ---------------------------------------------------------------------------
// Retention attention, split-bf16 MFMA, pre-split inputs.
// qt balanced: (bh & 8) ? x : 31-x so co-resident pairs sum to ~33 s-tiles.
// Output: RG split hi/lo bf16 [B,N,E].
// ---------------------------------------------------------------------------
__global__ __launch_bounds__(256) void attn_kernel(
    const short* __restrict__ Qh_g, const short* __restrict__ Ql_g,
    const short* __restrict__ Kh_g, const short* __restrict__ Kl_g,
    const short* __restrict__ Vth_g, const short* __restrict__ Vtl_g,
    const float* __restrict__ G,
    short* __restrict__ RGh, short* __restrict__ RGl)
{
    __shared__ short QhS[64 * 72], QlS[64 * 72];
    __shared__ short KhS[64 * 72], KlS[64 * 72];
    __shared__ short VhS[64 * 72], VlS[64 * 72];
    __shared__ short PhS[64 * 72], PlS[64 * 72];

    const int t = threadIdx.x, lane = t & 63, wv = t >> 6;
    const int quad = lane >> 4, l15 = lane & 15;
    const int bh = blockIdx.y, h = bh & 7, b = bh >> 3;
    const int qt = (bh & 8) ? blockIdx.x : (31 - blockIdx.x);
    const int n0 = qt * 64;
    const long base = (long)bh * 2048 * 64;

    float l2g;
    {
        float lg0 = logf(1.0f / 32.0f), lg1 = logf(1.0f / 512.0f);
        float gamma = 1.0f - expf(lg0 + (float)h * (lg1 - lg0) * (1.0f / 7.0f));
        l2g = log2f(gamma);
    }
    // gneg[sub*4+r] = gamma^-(sub*16+r)
    float gneg[16];
    #pragma unroll
    for (int i = 0; i < 16; ++i)
        gneg[i] = exp2f(-(float)((i >> 2) * 16 + (i & 3)) * l2g);

    const int srow = t >> 2;
    const int scol = (t & 3) * 16;
    const int n = n0 + wv * 16 + l15;   // this lane's q-row (for S^T)

    // stage Q tile
    {
        const long qo = base + (long)(n0 + srow) * 64 + scol;
        s16x8 a0 = *(const s16x8*)(Qh_g + qo);
        s16x8 a1 = *(const s16x8*)(Qh_g + qo + 8);
        s16x8 a2 = *(const s16x8*)(Ql_g + qo);
        s16x8 a3 = *(const s16x8*)(Ql_g + qo + 8);
        *(s16x8*)&QhS[srow * 72 + scol]     = a0;
        *(s16x8*)&QhS[srow * 72 + scol + 8] = a1;
        *(s16x8*)&QlS[srow * 72 + scol]     = a2;
        *(s16x8*)&QlS[srow * 72 + scol + 8] = a3;
    }
    __syncthreads();
    s16x8 qh[2], ql[2];
    qh[0] = *(const s16x8*)&QhS[(wv * 16 + l15) * 72 + quad * 8];
    qh[1] = *(const s16x8*)&QhS[(wv * 16 + l15) * 72 + quad * 8 + 32];
    ql[0] = *(const s16x8*)&QlS[(wv * 16 + l15) * 72 + quad * 8];
    ql[1] = *(const s16x8*)&QlS[(wv * 16 + l15) * 72 + quad * 8 + 32];

    f32x4 racc[4];
    #pragma unroll
    for (int i = 0; i < 4; ++i) racc[i] = (f32x4){0.f, 0.f, 0.f, 0.f};

    for (int st = 0; st <= qt; ++st) {
        const int s0 = st * 64;
        __syncthreads();   // previous iteration's K/V reads done
        {
            const long ko = base + (long)(s0 + srow) * 64 + scol;
            s16x8 a0 = *(const s16x8*)(Kh_g + ko);
            s16x8 a1 = *(const s16x8*)(Kh_g + ko + 8);
            s16x8 a2 = *(const s16x8*)(Kl_g + ko);
            s16x8 a3 = *(const s16x8*)(Kl_g + ko + 8);
            *(s16x8*)&KhS[srow * 72 + scol]     = a0;
            *(s16x8*)&KhS[srow * 72 + scol + 8] = a1;
            *(s16x8*)&KlS[srow * 72 + scol]     = a2;
            *(s16x8*)&KlS[srow * 72 + scol + 8] = a3;

            const long vo = base + (long)srow * 2048 + s0 + scol;
            s16x8 b0 = *(const s16x8*)(Vth_g + vo);
            s16x8 b1 = *(const s16x8*)(Vth_g + vo + 8);
            s16x8 b2 = *(const s16x8*)(Vtl_g + vo);
            s16x8 b3 = *(const s16x8*)(Vtl_g + vo + 8);
            *(s16x8*)&VhS[srow * 72 + scol]     = b0;
            *(s16x8*)&VhS[srow * 72 + scol + 8] = b1;
            *(s16x8*)&VlS[srow * 72 + scol]     = b2;
            *(s16x8*)&VlS[srow * 72 + scol + 8] = b3;
        }
        __syncthreads();

        // per-s-tile decay base: gamma^(n - s0 - quad*4)
        const float t0 = exp2f((float)(n - s0 - quad * 4) * l2g);

        // S^T = K · Q^T, split product
        #pragma unroll
        for (int sub = 0; sub < 4; ++sub) {
            const int ro = (sub * 16 + l15) * 72 + quad * 8;
            s16x8 kh0 = *(const s16x8*)&KhS[ro];
            s16x8 kh1 = *(const s16x8*)&KhS[ro + 32];
            s16x8 kl0 = *(const s16x8*)&KlS[ro];
            s16x8 kl1 = *(const s16x8*)&KlS[ro + 32];
            f32x4 sacc = (f32x4){0.f, 0.f, 0.f, 0.f};
            sacc = __builtin_amdgcn_mfma_f32_16x16x32_bf16(kh0, qh[0], sacc, 0, 0, 0);
            sacc = __builtin_amdgcn_mfma_f32_16x16x32_bf16(kh1, qh[1], sacc, 0, 0, 0);
            sacc = __builtin_amdgcn_mfma_f32_16x16x32_bf16(kl0, qh[0], sacc, 0, 0, 0);
            sacc = __builtin_amdgcn_mfma_f32_16x16x32_bf16(kl1, qh[1], sacc, 0, 0, 0);
            sacc = __builtin_amdgcn_mfma_f32_16x16x32_bf16(kh0, ql[0], sacc, 0, 0, 0);
            sacc = __builtin_amdgcn_mfma_f32_16x16x32_bf16(kh1, ql[1], sacc, 0, 0, 0);

            const int sb = s0 + sub * 16 + quad * 4;
            s16x4 pkh, pkl;
            #pragma unroll
            for (int r = 0; r < 4; ++r) {
                const int s = sb + r;
                const float wgt = (n >= s) ? t0 * gneg[sub * 4 + r] : 0.0f;
                const float p = sacc[r] * wgt;
                short hb = f2bf(p);
                pkh[r] = hb;
                pkl[r] = f2bf(p - bf2f(hb));
            }
            const int po = (wv * 16 + l15) * 72 + sub * 16 + quad * 4;
            *(s16x4*)&PhS[po] = pkh;
            *(s16x4*)&PlS[po] = pkl;
        }

        // ret += P · V  (wave-private P rows)
        const int pro = (wv * 16 + l15) * 72 + quad * 8;
        s16x8 ph0 = *(const s16x8*)&PhS[pro];
        s16x8 ph1 = *(const s16x8*)&PhS[pro + 32];
        s16x8 pl0 = *(const s16x8*)&PlS[pro];
        s16x8 pl1 = *(const s16x8*)&PlS[pro + 32];
        #pragma unroll
        for (int ds = 0; ds < 4; ++ds) {
            const int ro = (ds * 16 + l15) * 72 + quad * 8;
            s16x8 vh0 = *(const s16x8*)&VhS[ro];
            s16x8 vh1 = *(const s16x8*)&VhS[ro + 32];
            s16x8 vl0 = *(const s16x8*)&VlS[ro];
            s16x8 vl1 = *(const s16x8*)&VlS[ro + 32];
            racc[ds] = __builtin_amdgcn_mfma_f32_16x16x32_bf16(ph0, vh0, racc[ds], 0, 0, 0);
            racc[ds] = __builtin_amdgcn_mfma_f32_16x16x32_bf16(ph1, vh1, racc[ds], 0, 0, 0);
            racc[ds] = __builtin_amdgcn_mfma_f32_16x16x32_bf16(pl0, vh0, racc[ds], 0, 0, 0);
            racc[ds] = __builtin_amdgcn_mfma_f32_16x16x32_bf16(pl1, vh1, racc[ds], 0, 0, 0);
            racc[ds] = __builtin_amdgcn_mfma_f32_16x16x32_bf16(ph0, vl0, racc[ds], 0, 0, 0);
            racc[ds] = __builtin_amdgcn_mfma_f32_16x16x32_bf16(ph1, vl1, racc[ds], 0, 0, 0);
        }
    }

    // GroupNorm over d per q-row, gate, split-store RG
    float mean[4], rstd[4];
    #pragma unroll
    for (int r = 0; r < 4; ++r) {
        float s = racc[0][r] + racc[1][r] + racc[2][r] + racc[3][r];
        s += __shfl_xor(s, 1); s += __shfl_xor(s, 2);
        s += __shfl_xor(s, 4); s += __shfl_xor(s, 8);
        mean[r] = s * (1.0f / 64.0f);
        float vs = 0.f;
        #pragma unroll
        for (int ds = 0; ds < 4; ++ds) {
            float d = racc[ds][r] - mean[r];
            vs += d * d;
        }
        vs += __shfl_xor(vs, 1); vs += __shfl_xor(vs, 2);
        vs += __shfl_xor(vs, 4); vs += __shfl_xor(vs, 8);
        rstd[r] = rsqrtf(vs * (1.0f / 64.0f) + 1e-6f);
    }
    #pragma unroll
    for (int ds = 0; ds < 4; ++ds) {
        #pragma unroll
        for (int r = 0; r < 4; ++r) {
            const int nn = n0 + wv * 16 + quad * 4 + r;
            const int d = ds * 16 + l15;
            const long gi = ((long)(b * 2048 + nn)) * 512 + h * 64 + d;
            const float rg = (racc[ds][r] - mean[r]) * rstd[r] * G[gi];
            short hb = f2bf(rg);
            RGh[gi] = hb;
            RGl[gi] = f2bf(rg - bf2f(hb));
        }
    }
}

// ---------------------------------------------------------------------------
// Output projection: out = RG @ Wo^T + bo, RG pre-split, Wo pre-split.
// 64x128 tile, 4 waves 2x2 (wave tile 32x64), BK=32. 256 blocks.
// ---------------------------------------------------------------------------
__global__ __launch_bounds__(256) void projo_kernel(
    const short* __restrict__ RGh, const short* __restrict__ RGl,
    const short* __restrict__ Woh_g, const float* __restrict__ bo,
    float* __restrict__ out)
{
    __shared__ short XhS[64 * 40], XlS[64 * 40];
    __shared__ short WhS[128 * 40], WlS[128 * 40];

    const short* Wol_g = Woh_g + 262144;
    const int t = threadIdx.x, lane = t & 63, wv = t >> 6;
    const int wm = wv >> 1, wn = wv & 1;
    const int quad = lane >> 4, l15 = lane & 15;
    const int m0 = blockIdx.y * 64, n0 = blockIdx.x * 128;

    f32x4 acc[2][4];
    #pragma unroll
    for (int i = 0; i < 2; ++i)
        #pragma unroll
        for (int j = 0; j < 4; ++j)
            acc[i][j] = (f32x4){0.f, 0.f, 0.f, 0.f};

    for (int k0 = 0; k0 < 512; k0 += 32) {
        __syncthreads();
        {
            const int xr = t >> 2, xc = (t & 3) * 8;
            const long xo = (long)(m0 + xr) * 512 + k0 + xc;
            *(s16x8*)&XhS[xr * 40 + xc] = *(const s16x8*)(RGh + xo);
            *(s16x8*)&XlS[xr * 40 + xc] = *(const s16x8*)(RGl + xo);

            const int wr = t >> 1, wc = (t & 1) * 16;
            const long wo = (long)(n0 + wr) * 512 + k0 + wc;
            s16x8 w0 = *(const s16x8*)(Woh_g + wo);
            s16x8 w1 = *(const s16x8*)(Woh_g + wo + 8);
            s16x8 w2 = *(const s16x8*)(Wol_g + wo);
            s16x8 w3 = *(const s16x8*)(Wol_g + wo + 8);
            *(s16x8*)&WhS[wr * 40 + wc]     = w0;
            *(s16x8*)&WhS[wr * 40 + wc + 8] = w1;
            *(s16x8*)&WlS[wr * 40 + wc]     = w2;
            *(s16x8*)&WlS[wr * 40 + wc + 8] = w3;
        }
        __syncthreads();

        s16x8 ah[2], al[2], bh[4], bl[4];
        #pragma unroll
        for (int s = 0; s < 2; ++s) {
            const int ro = (wm * 32 + s * 16 + l15) * 40 + quad * 8;
            ah[s] = *(const s16x8*)&XhS[ro];
            al[s] = *(const s16x8*)&XlS[ro];
        }
        #pragma unroll
        for (int s = 0; s < 4; ++s) {
            const int ro = (wn * 64 + s * 16 + l15) * 40 + quad * 8;
            bh[s] = *(const s16x8*)&WhS[ro];
            bl[s] = *(const s16x8*)&WlS[ro];
        }
        #pragma unroll
        for (int i = 0; i < 2; ++i)
            #pragma unroll
            for (int j = 0; j < 4; ++j) {
                acc[i][j] = __builtin_amdgcn_mfma_f32_16x16x32_bf16(ah[i], bh[j], acc[i][j], 0, 0, 0);
                acc[i][j] = __builtin_amdgcn_mfma_f32_16x16x32_bf16(al[i], bh[j], acc[i][j], 0, 0, 0);
                acc[i][j] = __builtin_amdgcn_mfma_f32_16x16x32_bf16(ah[i], bl[j], acc[i][j], 0, 0, 0);
            }
    }

    #pragma unroll
    for (int ns = 0; ns < 4; ++ns) {
        const int col = n0 + wn * 64 + ns * 16 + l15;
        const float bvv = bo[col];
        #pragma unroll
        for (int ms = 0; ms < 2; ++ms) {
            #pragma unroll
            for (int r = 0; r < 4; ++r) {
                const int m = m0 + wm * 32 + ms * 16 + quad * 4 + r;
                out[(long)m * 512 + col] = acc[ms][ns][r] + bvv;
            }
        }
    }
}

extern "C" void kernel_launch(void* const* d_in, const int* in_sizes, int n_in,
                              void* d_out, int out_size, void* d_ws, size_t ws_size,
                              hipStream_t stream) {
    const float* query = (const float*)d_in[0];
    const float* kin   = (const float*)d_in[1];
    const float* vin   = (const float*)d_in[2];
    const float* Wq = (const float*)d_in[3];
    const float* bq = (const float*)d_in[4];
    const float* Wk = (const float*)d_in[5];
    const float* bk = (const float*)d_in[6];
    const float* Wv = (const float*)d_in[7];
    const float* bv = (const float*)d_in[8];
    const float* Wg = (const float*)d_in[9];
    const float* bg = (const float*)d_in[10];
    const float* Wo = (const float*)d_in[11];
    const float* bo = (const float*)d_in[12];

    short* S = (short*)d_ws;
    const long NE = 2097152;             // 4096*512 elements
    short* WSp = S;                      // 5 * 524288 shorts
    short* Qh  = S + 2621440;
    short* Ql  = Qh + NE;
    short* Kh  = Ql + NE;
    short* Kl  = Kh + NE;
    short* Vth = Kl + NE;
    short* Vtl = Vth + NE;
    float* G   = (float*)(Vtl + NE);     // NE floats
    short* RGh = (short*)(G + NE);       // also V0h (pre-transpose V)
    short* RGl = RGh + NE;               // also V0l

    wsplit_kernel<<<320, 256, 0, stream>>>(Wq, Wk, Wv, Wg, Wo, WSp);
    projqkvg_kernel<<<dim3(4, 32, 4), 256, 0, stream>>>(
        query, kin, vin, WSp, bq, bk, bv, bg,
        Qh, Ql, Kh, Kl, RGh, RGl, G);
    vtrans_kernel<<<dim3(32, 16), 256, 0, stream>>>(RGh, RGl, Vth, Vtl);
    attn_kernel<<<dim3(32, 16), 256, 0, stream>>>(
        Qh, Ql, Kh, Kl, Vth, Vtl, G, RGh, RGl);
    projo_kernel<<<dim3(4, 64), 256, 0, stream>>>(
        RGh, RGl, WSp + 4 * 524288, bo, (float*)d_out);
}

// Round 5
// 331.396 us; speedup vs baseline: 2.2465x; 1.0051x over previous
//
#include <hip/hip_runtime.h>
#include <math.h>

typedef float f32x4 __attribute__((ext_vector_type(4)));
typedef short s16x8 __attribute__((ext_vector_type(8)));
typedef short s16x4 __attribute__((ext_vector_type(4)));

__device__ __forceinline__ short f2bf(float f) {
    unsigned u = __builtin_bit_cast(unsigned, f);
    unsigned r = u + 0x7FFFu + ((u >> 16) & 1u);
    return (short)(r >> 16);
}
__device__ __forceinline__ float bf2f(short h) {
    return __builtin_bit_cast(float, ((unsigned)(unsigned short)h) << 16);
}
__device__ __forceinline__ unsigned pack2(short a, short b) {
    return (unsigned)(unsigned short)a | ((unsigned)(unsigned short)b << 16);
}

// split 16 contiguous fp32 at p into hi/lo bf16 at hi[0..15], lo[0..15]
__device__ __forceinline__ void split16(const float* __restrict__ p,
                                        short* hi, short* lo) {
    f32x4 a0 = *(const f32x4*)(p);
    f32x4 a1 = *(const f32x4*)(p + 4);
    f32x4 a2 = *(const f32x4*)(p + 8);
    f32x4 a3 = *(const f32x4*)(p + 12);
    s16x8 h0, h1, l0, l1;
    #pragma unroll
    for (int i = 0; i < 4; ++i) {
        short h;
        h = f2bf(a0[i]); h0[i]     = h; l0[i]     = f2bf(a0[i] - bf2f(h));
        h = f2bf(a1[i]); h0[4 + i] = h; l0[4 + i] = f2bf(a1[i] - bf2f(h));
        h = f2bf(a2[i]); h1[i]     = h; l1[i]     = f2bf(a2[i] - bf2f(h));
        h = f2bf(a3[i]); h1[4 + i] = h; l1[4 + i] = f2bf(a3[i] - bf2f(h));
    }
    *(s16x8*)hi       = h0;
    *(s16x8*)(hi + 8) = h1;
    *(s16x8*)lo       = l0;
    *(s16x8*)(lo + 8) = l1;
}

// ---------------------------------------------------------------------------
// Pre-split the 5 weight matrices into hi/lo bf16 planes.
// ---------------------------------------------------------------------------
__global__ __launch_bounds__(256) void wsplit_kernel(
    const float* __restrict__ W0, const float* __restrict__ W1,
    const float* __restrict__ W2, const float* __restrict__ W3,
    const float* __restrict__ W4, short* __restrict__ outbase)
{
    const int blk = blockIdx.x;          // 64 blocks per W
    const int w = blk >> 6;
    const int bi = blk & 63;
    const float* src = (w == 0) ? W0 : (w == 1) ? W1 : (w == 2) ? W2
                      : (w == 3) ? W3 : W4;
    short* hi = outbase + (long)w * 524288;
    short* lo = hi + 262144;
    const int idx = (bi * 256 + threadIdx.x) * 16;
    split16(src + idx, hi + idx, lo + idx);
}

// ---------------------------------------------------------------------------
// Fused Q/K/V/G projections, blockIdx.z = mode. 128x128 tile, 4 waves 2x2.
// mode 0: Q rotary -> split [B,H,N,D]; 1: K rotary*0.125 -> split [B,H,N,D];
// mode 2: V -> split TRANSPOSED [B,H,D,N]; 3: G silu -> fp32 [B,N,E]
// All stores LDS-assembled for full-cacheline coalescing.
// ---------------------------------------------------------------------------
__global__ __launch_bounds__(256) void projqkvg_kernel(
    const float* __restrict__ Xq, const float* __restrict__ Xk,
    const float* __restrict__ Xv, const short* __restrict__ Wsp,
    const float* __restrict__ bq, const float* __restrict__ bk,
    const float* __restrict__ bv, const float* __restrict__ bg,
    short* __restrict__ Qh, short* __restrict__ Ql,
    short* __restrict__ Kh, short* __restrict__ Kl,
    short* __restrict__ Vth, short* __restrict__ Vtl,
    float* __restrict__ G)
{
    __shared__ __align__(16) short SB[20480];   // 40 KB
    short* XhS = SB;            // 128*40
    short* XlS = SB + 5120;
    short* WhS = SB + 10240;
    short* WlS = SB + 15360;

    const int mode = blockIdx.z;
    const float* X = (mode == 1) ? Xk : (mode == 2) ? Xv : Xq;
    const short* Wh_g = Wsp + (long)mode * 524288;
    const short* Wl_g = Wh_g + 262144;
    const float* bias = (mode == 0) ? bq : (mode == 1) ? bk
                       : (mode == 2) ? bv : bg;

    const int t = threadIdx.x, lane = t & 63, wv = t >> 6;
    const int wm = wv >> 1, wn = wv & 1;
    const int quad = lane >> 4, l15 = lane & 15;
    const int m0 = blockIdx.y * 128, n0 = blockIdx.x * 128;

    f32x4 acc[4][4];
    #pragma unroll
    for (int i = 0; i < 4; ++i)
        #pragma unroll
        for (int j = 0; j < 4; ++j)
            acc[i][j] = (f32x4){0.f, 0.f, 0.f, 0.f};

    const int srow = t >> 1;
    const int scol = (t & 1) * 16;

    for (int k0 = 0; k0 < 512; k0 += 32) {
        __syncthreads();
        split16(X + (long)(m0 + srow) * 512 + k0 + scol,
                &XhS[srow * 40 + scol], &XlS[srow * 40 + scol]);
        {
            const long wo = (long)(n0 + srow) * 512 + k0 + scol;
            s16x8 w0 = *(const s16x8*)(Wh_g + wo);
            s16x8 w1 = *(const s16x8*)(Wh_g + wo + 8);
            s16x8 w2 = *(const s16x8*)(Wl_g + wo);
            s16x8 w3 = *(const s16x8*)(Wl_g + wo + 8);
            *(s16x8*)&WhS[srow * 40 + scol]     = w0;
            *(s16x8*)&WhS[srow * 40 + scol + 8] = w1;
            *(s16x8*)&WlS[srow * 40 + scol]     = w2;
            *(s16x8*)&WlS[srow * 40 + scol + 8] = w3;
        }
        __syncthreads();

        s16x8 ah[4], al[4], bh[4], bl[4];
        #pragma unroll
        for (int s = 0; s < 4; ++s) {
            const int ro = (wm * 64 + s * 16 + l15) * 40 + quad * 8;
            ah[s] = *(const s16x8*)&XhS[ro];
            al[s] = *(const s16x8*)&XlS[ro];
        }
        #pragma unroll
        for (int s = 0; s < 4; ++s) {
            const int ro = (wn * 64 + s * 16 + l15) * 40 + quad * 8;
            bh[s] = *(const s16x8*)&WhS[ro];
            bl[s] = *(const s16x8*)&WlS[ro];
        }
        #pragma unroll
        for (int i = 0; i < 4; ++i)
            #pragma unroll
            for (int j = 0; j < 4; ++j) {
                acc[i][j] = __builtin_amdgcn_mfma_f32_16x16x32_bf16(ah[i], bh[j], acc[i][j], 0, 0, 0);
                acc[i][j] = __builtin_amdgcn_mfma_f32_16x16x32_bf16(al[i], bh[j], acc[i][j], 0, 0, 0);
                acc[i][j] = __builtin_amdgcn_mfma_f32_16x16x32_bf16(ah[i], bl[j], acc[i][j], 0, 0, 0);
            }
    }

    __syncthreads();   // staging LDS reads done everywhere; safe to reuse LDS

    const int hcol = (n0 + wn * 64) >> 6;   // one head per wave column span

    if (mode <= 1) {
        // ms-chunked: 16-row hi+lo tiles per wave, stride 72
        short* Thi = SB + wv * 2304;
        short* Tlo = Thi + 1152;
        short* OH = (mode == 0) ? Qh : Kh;
        short* OL = (mode == 0) ? Ql : Kl;
        #pragma unroll
        for (int ms = 0; ms < 4; ++ms) {
            #pragma unroll
            for (int ns = 0; ns < 4; ++ns) {
                const int col = n0 + wn * 64 + ns * 16 + l15;
                const float bvv = bias[col];
                const int pp = (col & 63) >> 1;
                const float theta = powf(10000.0f, -(float)pp * (1.0f / 31.0f));
                #pragma unroll
                for (int r = 0; r < 4; ++r) {
                    const int m = m0 + wm * 64 + ms * 16 + quad * 4 + r;
                    const int pos = m & 2047;
                    float x = acc[ms][ns][r] + bvv;
                    float prt = __shfl_xor(x, 1);   // full-exec shuffle
                    float ang = (float)pos * theta;
                    float sv = sinf(ang), cv = cosf(ang);
                    float y0 = x * cv - prt * sv;
                    float y1 = prt * cv + x * sv;
                    if (mode == 1) { y0 *= 0.125f; y1 *= 0.125f; }
                    if (!(l15 & 1)) {
                        short h0 = f2bf(y0), h1 = f2bf(y1);
                        short l0 = f2bf(y0 - bf2f(h0)), l1 = f2bf(y1 - bf2f(h1));
                        const int o = (quad * 4 + r) * 72 + ns * 16 + l15;
                        *(unsigned*)&Thi[o] = pack2(h0, h1);
                        *(unsigned*)&Tlo[o] = pack2(l0, l1);
                    }
                }
            }
            const int mb = m0 + wm * 64 + ms * 16;
            const int bb = mb >> 11, posb = mb & 2047;
            #pragma unroll
            for (int p2 = 0; p2 < 2; ++p2) {
                const int row = p2 * 8 + (lane >> 3);
                const int ch = (lane & 7) * 8;
                s16x8 vh = *(const s16x8*)&Thi[row * 72 + ch];
                s16x8 vl = *(const s16x8*)&Tlo[row * 72 + ch];
                const long o = ((long)(bb * 8 + hcol) * 2048 + posb + row) * 64 + ch;
                *(s16x8*)(OH + o) = vh;
                *(s16x8*)(OL + o) = vl;
            }
        }
    } else if (mode == 2) {
        // transposed tile T2[col(d)][row(token)], stride 72; one plane at a time
        short* T2 = SB + wv * 4608;
        const int mb = m0 + wm * 64;
        const int bb = mb >> 11, posb = mb & 2047;
        #pragma unroll
        for (int pl = 0; pl < 2; ++pl) {
            #pragma unroll
            for (int ns = 0; ns < 4; ++ns) {
                const int col = n0 + wn * 64 + ns * 16 + l15;
                const float bvv = bias[col];
                #pragma unroll
                for (int ms = 0; ms < 4; ++ms) {
                    s16x4 pk;
                    #pragma unroll
                    for (int r = 0; r < 4; ++r) {
                        float x = acc[ms][ns][r] + bvv;
                        short hb = f2bf(x);
                        pk[r] = pl ? f2bf(x - bf2f(hb)) : hb;
                    }
                    *(s16x4*)&T2[(ns * 16 + l15) * 72 + ms * 16 + quad * 4] = pk;
                }
            }
            short* dst = pl ? Vtl : Vth;
            #pragma unroll
            for (int it = 0; it < 8; ++it) {
                const int d = it * 8 + (lane >> 3);
                const int ch = (lane & 7) * 8;
                s16x8 v = *(const s16x8*)&T2[d * 72 + ch];
                const long o = ((long)(bb * 8 + hcol) * 64 + d) * 2048 + posb + ch;
                *(s16x8*)(dst + o) = v;
            }
        }
    } else {
        // G: silu, fp32, direct (row-major; lines filled by adjacent ns stores)
        #pragma unroll
        for (int ns = 0; ns < 4; ++ns) {
            const int col = n0 + wn * 64 + ns * 16 + l15;
            const float bvv = bias[col];
            #pragma unroll
            for (int ms = 0; ms < 4; ++ms)
                #pragma unroll
                for (int r = 0; r < 4; ++r) {
                    const int m = m0 + wm * 64 + ms * 16 + quad * 4 + r;
                    float x = acc[ms][ns][r] + bvv;
                    G[(long)m * 512 + col] = x / (1.0f + expf(-x));
                }
        }
    }
}

// ---------------------------------------------------------------------------
// Retention attention, split-bf16 MFMA, pre-split inputs.
// Q fragments loaded directly from global; K/V staged; P stride-68.
// RG output LDS-assembled into coalesced 128B-row stores.
// ---------------------------------------------------------------------------
__global__ __launch_bounds__(256) void attn_kernel(
    const short* __restrict__ Qh_g, const short* __restrict__ Ql_g,
    const short* __restrict__ Kh_g, const short* __restrict__ Kl_g,
    const short* __restrict__ Vth_g, const short* __restrict__ Vtl_g,
    const float* __restrict__ G,
    short* __restrict__ RGh, short* __restrict__ RGl)
{
    __shared__ __align__(16) short KhS[64 * 72], KlS[64 * 72];
    __shared__ __align__(16) short VhS[64 * 72], VlS[64 * 72];
    __shared__ __align__(16) short PhS[64 * 68], PlS[64 * 68];

    const int t = threadIdx.x, lane = t & 63, wv = t >> 6;
    const int quad = lane >> 4, l15 = lane & 15;
    const int bh = blockIdx.y, h = bh & 7, b = bh >> 3;
    const int qt = (bh & 8) ? blockIdx.x : (31 - blockIdx.x);
    const int n0 = qt * 64;
    const long base = (long)bh * 2048 * 64;

    float l2g;
    {
        float lg0 = logf(1.0f / 32.0f), lg1 = logf(1.0f / 512.0f);
        float gamma = 1.0f - expf(lg0 + (float)h * (lg1 - lg0) * (1.0f / 7.0f));
        l2g = log2f(gamma);
    }
    float gneg[16];
    #pragma unroll
    for (int i = 0; i < 16; ++i)
        gneg[i] = exp2f(-(float)((i >> 2) * 16 + (i & 3)) * l2g);

    const int srow = t >> 2;
    const int scol = (t & 3) * 16;
    const int n = n0 + wv * 16 + l15;

    // Q fragments: direct global loads (one-time, L2-served)
    s16x8 qh[2], ql[2];
    {
        const short* qp = Qh_g + base + (long)(n0 + wv * 16 + l15) * 64 + quad * 8;
        const short* qp2 = Ql_g + base + (long)(n0 + wv * 16 + l15) * 64 + quad * 8;
        qh[0] = *(const s16x8*)qp;
        qh[1] = *(const s16x8*)(qp + 32);
        ql[0] = *(const s16x8*)qp2;
        ql[1] = *(const s16x8*)(qp2 + 32);
    }

    f32x4 racc[4];
    #pragma unroll
    for (int i = 0; i < 4; ++i) racc[i] = (f32x4){0.f, 0.f, 0.f, 0.f};

    for (int st = 0; st <= qt; ++st) {
        const int s0 = st * 64;
        __syncthreads();
        {
            const long ko = base + (long)(s0 + srow) * 64 + scol;
            s16x8 a0 = *(const s16x8*)(Kh_g + ko);
            s16x8 a1 = *(const s16x8*)(Kh_g + ko + 8);
            s16x8 a2 = *(const s16x8*)(Kl_g + ko);
            s16x8 a3 = *(const s16x8*)(Kl_g + ko + 8);
            *(s16x8*)&KhS[srow * 72 + scol]     = a0;
            *(s16x8*)&KhS[srow * 72 + scol + 8] = a1;
            *(s16x8*)&KlS[srow * 72 + scol]     = a2;
            *(s16x8*)&KlS[srow * 72 + scol + 8] = a3;

            const long vo = base + (long)srow * 2048 + s0 + scol;
            s16x8 b0 = *(const s16x8*)(Vth_g + vo);
            s16x8 b1 = *(const s16x8*)(Vth_g + vo + 8);
            s16x8 b2 = *(const s16x8*)(Vtl_g + vo);
            s16x8 b3 = *(const s16x8*)(Vtl_g + vo + 8);
            *(s16x8*)&VhS[srow * 72 + scol]     = b0;
            *(s16x8*)&VhS[srow * 72 + scol + 8] = b1;
            *(s16x8*)&VlS[srow * 72 + scol]     = b2;
            *(s16x8*)&VlS[srow * 72 + scol + 8] = b3;
        }
        __syncthreads();

        const float t0 = exp2f((float)(n - s0 - quad * 4) * l2g);

        #pragma unroll
        for (int sub = 0; sub < 4; ++sub) {
            const int ro = (sub * 16 + l15) * 72 + quad * 8;
            s16x8 kh0 = *(const s16x8*)&KhS[ro];
            s16x8 kh1 = *(const s16x8*)&KhS[ro + 32];
            s16x8 kl0 = *(const s16x8*)&KlS[ro];
            s16x8 kl1 = *(const s16x8*)&KlS[ro + 32];
            f32x4 sacc = (f32x4){0.f, 0.f, 0.f, 0.f};
            sacc = __builtin_amdgcn_mfma_f32_16x16x32_bf16(kh0, qh[0], sacc, 0, 0, 0);
            sacc = __builtin_amdgcn_mfma_f32_16x16x32_bf16(kh1, qh[1], sacc, 0, 0, 0);
            sacc = __builtin_amdgcn_mfma_f32_16x16x32_bf16(kl0, qh[0], sacc, 0, 0, 0);
            sacc = __builtin_amdgcn_mfma_f32_16x16x32_bf16(kl1, qh[1], sacc, 0, 0, 0);
            sacc = __builtin_amdgcn_mfma_f32_16x16x32_bf16(kh0, ql[0], sacc, 0, 0, 0);
            sacc = __builtin_amdgcn_mfma_f32_16x16x32_bf16(kh1, ql[1], sacc, 0, 0, 0);

            const int sb = s0 + sub * 16 + quad * 4;
            s16x4 pkh, pkl;
            #pragma unroll
            for (int r = 0; r < 4; ++r) {
                const int s = sb + r;
                const float wgt = (n >= s) ? t0 * gneg[sub * 4 + r] : 0.0f;
                const float p = sacc[r] * wgt;
                short hb = f2bf(p);
                pkh[r] = hb;
                pkl[r] = f2bf(p - bf2f(hb));
            }
            const int po = (wv * 16 + l15) * 68 + sub * 16 + quad * 4;
            *(s16x4*)&PhS[po] = pkh;
            *(s16x4*)&PlS[po] = pkl;
        }

        const int pro = (wv * 16 + l15) * 68 + quad * 8;
        s16x8 ph0 = *(const s16x8*)&PhS[pro];
        s16x8 ph1 = *(const s16x8*)&PhS[pro + 32];
        s16x8 pl0 = *(const s16x8*)&PlS[pro];
        s16x8 pl1 = *(const s16x8*)&PlS[pro + 32];
        #pragma unroll
        for (int ds = 0; ds < 4; ++ds) {
            const int ro = (ds * 16 + l15) * 72 + quad * 8;
            s16x8 vh0 = *(const s16x8*)&VhS[ro];
            s16x8 vh1 = *(const s16x8*)&VhS[ro + 32];
            s16x8 vl0 = *(const s16x8*)&VlS[ro];
            s16x8 vl1 = *(const s16x8*)&VlS[ro + 32];
            racc[ds] = __builtin_amdgcn_mfma_f32_16x16x32_bf16(ph0, vh0, racc[ds], 0, 0, 0);
            racc[ds] = __builtin_amdgcn_mfma_f32_16x16x32_bf16(ph1, vh1, racc[ds], 0, 0, 0);
            racc[ds] = __builtin_amdgcn_mfma_f32_16x16x32_bf16(pl0, vh0, racc[ds], 0, 0, 0);
            racc[ds] = __builtin_amdgcn_mfma_f32_16x16x32_bf16(pl1, vh1, racc[ds], 0, 0, 0);
            racc[ds] = __builtin_amdgcn_mfma_f32_16x16x32_bf16(ph0, vl0, racc[ds], 0, 0, 0);
            racc[ds] = __builtin_amdgcn_mfma_f32_16x16x32_bf16(ph1, vl1, racc[ds], 0, 0, 0);
        }
    }

    // GroupNorm per q-row, gate, assemble in LDS, coalesced store
    float mean[4], rstd[4];
    #pragma unroll
    for (int r = 0; r < 4; ++r) {
        float s = racc[0][r] + racc[1][r] + racc[2][r] + racc[3][r];
        s += __shfl_xor(s, 1); s += __shfl_xor(s, 2);
        s += __shfl_xor(s, 4); s += __shfl_xor(s, 8);
        mean[r] = s * (1.0f / 64.0f);
        float vs = 0.f;
        #pragma unroll
        for (int ds = 0; ds < 4; ++ds) {
            float d = racc[ds][r] - mean[r];
            vs += d * d;
        }
        vs += __shfl_xor(vs, 1); vs += __shfl_xor(vs, 2);
        vs += __shfl_xor(vs, 4); vs += __shfl_xor(vs, 8);
        rstd[r] = rsqrtf(vs * (1.0f / 64.0f) + 1e-6f);
    }

    __syncthreads();   // all waves done with K tiles; reuse for RG assembly
    short* rgH = KhS + wv * 1152;   // 16 rows x 72
    short* rgL = KlS + wv * 1152;
    #pragma unroll
    for (int ds = 0; ds < 4; ++ds) {
        #pragma unroll
        for (int r = 0; r < 4; ++r) {
            const int nn = n0 + wv * 16 + quad * 4 + r;
            const int d = ds * 16 + l15;
            const long gi = ((long)(b * 2048 + nn)) * 512 + h * 64 + d;
            float rg = (racc[ds][r] - mean[r]) * rstd[r] * G[gi];
            float prt = __shfl_xor(rg, 1);
            if (!(l15 & 1)) {
                short h0 = f2bf(rg), h1 = f2bf(prt);
                short l0 = f2bf(rg - bf2f(h0)), l1 = f2bf(prt - bf2f(h1));
                const int o = (quad * 4 + r) * 72 + ds * 16 + l15;
                *(unsigned*)&rgH[o] = pack2(h0, h1);
                *(unsigned*)&rgL[o] = pack2(l0, l1);
            }
        }
    }
    #pragma unroll
    for (int p2 = 0; p2 < 2; ++p2) {
        const int row = p2 * 8 + (lane >> 3);
        const int ch = (lane & 7) * 8;
        s16x8 vh = *(const s16x8*)&rgH[row * 72 + ch];
        s16x8 vl = *(const s16x8*)&rgL[row * 72 + ch];
        const int nn = n0 + wv * 16 + row;
        const long o = ((long)(b * 2048 + nn)) * 512 + h * 64 + ch;
        *(s16x8*)(RGh + o) = vh;
        *(s16x8*)(RGl + o) = vl;
    }
}

// ---------------------------------------------------------------------------
// Output projection: out = RG @ Wo^T + bo. 64x128 tile, waves 2x2 (32x64).
// fp32 output LDS-assembled for coalescing.
// ---------------------------------------------------------------------------
__global__ __launch_bounds__(256) void projo_kernel(
    const short* __restrict__ RGh, const short* __restrict__ RGl,
    const short* __restrict__ Woh_g, const float* __restrict__ bo,
    float* __restrict__ out)
{
    __shared__ __align__(16) char PB[34816];
    short* XhS = (short*)PB;            // 64*40
    short* XlS = XhS + 2560;
    short* WhS = XhS + 5120;            // 128*40
    short* WlS = XhS + 10240;

    const short* Wol_g = Woh_g + 262144;
    const int t = threadIdx.x, lane = t & 63, wv = t >> 6;
    const int wm = wv >> 1, wn = wv & 1;
    const int quad = lane >> 4, l15 = lane & 15;
    const int m0 = blockIdx.y * 64, n0 = blockIdx.x * 128;

    f32x4 acc[2][4];
    #pragma unroll
    for (int i = 0; i < 2; ++i)
        #pragma unroll
        for (int j = 0; j < 4; ++j)
            acc[i][j] = (f32x4){0.f, 0.f, 0.f, 0.f};

    for (int k0 = 0; k0 < 512; k0 += 32) {
        __syncthreads();
        {
            const int xr = t >> 2, xc = (t & 3) * 8;
            const long xo = (long)(m0 + xr) * 512 + k0 + xc;
            *(s16x8*)&XhS[xr * 40 + xc] = *(const s16x8*)(RGh + xo);
            *(s16x8*)&XlS[xr * 40 + xc] = *(const s16x8*)(RGl + xo);

            const int wr = t >> 1, wc = (t & 1) * 16;
            const long wo = (long)(n0 + wr) * 512 + k0 + wc;
            s16x8 w0 = *(const s16x8*)(Woh_g + wo);
            s16x8 w1 = *(const s16x8*)(Woh_g + wo + 8);
            s16x8 w2 = *(const s16x8*)(Wol_g + wo);
            s16x8 w3 = *(const s16x8*)(Wol_g + wo + 8);
            *(s16x8*)&WhS[wr * 40 + wc]     = w0;
            *(s16x8*)&WhS[wr * 40 + wc + 8] = w1;
            *(s16x8*)&WlS[wr * 40 + wc]     = w2;
            *(s16x8*)&WlS[wr * 40 + wc + 8] = w3;
        }
        __syncthreads();

        s16x8 ah[2], al[2], bh[4], bl[4];
        #pragma unroll
        for (int s = 0; s < 2; ++s) {
            const int ro = (wm * 32 + s * 16 + l15) * 40 + quad * 8;
            ah[s] = *(const s16x8*)&XhS[ro];
            al[s] = *(const s16x8*)&XlS[ro];
        }
        #pragma unroll
        for (int s = 0; s < 4; ++s) {
            const int ro = (wn * 64 + s * 16 + l15) * 40 + quad * 8;
            bh[s] = *(const s16x8*)&WhS[ro];
            bl[s] = *(const s16x8*)&WlS[ro];
        }
        #pragma unroll
        for (int i = 0; i < 2; ++i)
            #pragma unroll
            for (int j = 0; j < 4; ++j) {
                acc[i][j] = __builtin_amdgcn_mfma_f32_16x16x32_bf16(ah[i], bh[j], acc[i][j], 0, 0, 0);
                acc[i][j] = __builtin_amdgcn_mfma_f32_16x16x32_bf16(al[i], bh[j], acc[i][j], 0, 0, 0);
                acc[i][j] = __builtin_amdgcn_mfma_f32_16x16x32_bf16(ah[i], bl[j], acc[i][j], 0, 0, 0);
            }
    }

    __syncthreads();
    float* T = (float*)PB + wv * 2176;   // 32 x 68 fp32
    #pragma unroll
    for (int ns = 0; ns < 4; ++ns) {
        const int col = n0 + wn * 64 + ns * 16 + l15;
        const float bvv = bo[col];
        #pragma unroll
        for (int ms = 0; ms < 2; ++ms)
            #pragma unroll
            for (int r = 0; r < 4; ++r)
                T[(ms * 16 + quad * 4 + r) * 68 + ns * 16 + l15] =
                    acc[ms][ns][r] + bvv;
    }
    #pragma unroll
    for (int it = 0; it < 4; ++it) {
        const int row = it * 8 + (lane >> 3);
        const int ch = (lane & 7) * 8;
        f32x4 a = *(const f32x4*)&T[row * 68 + ch];
        f32x4 c = *(const f32x4*)&T[row * 68 + ch + 4];
        const long o = (long)(m0 + wm * 32 + row) * 512 + n0 + wn * 64 + ch;
        *(f32x4*)(out + o) = a;
        *(f32x4*)(out + o + 4) = c;
    }
}

extern "C" void kernel_launch(void* const* d_in, const int* in_sizes, int n_in,
                              void* d_out, int out_size, void* d_ws, size_t ws_size,
                              hipStream_t stream) {
    const float* query = (const float*)d_in[0];
    const float* kin   = (const float*)d_in[1];
    const float* vin   = (const float*)d_in[2];
    const float* Wq = (const float*)d_in[3];
    const float* bq = (const float*)d_in[4];
    const float* Wk = (const float*)d_in[5];
    const float* bk = (const float*)d_in[6];
    const float* Wv = (const float*)d_in[7];
    const float* bv = (const float*)d_in[8];
    const float* Wg = (const float*)d_in[9];
    const float* bg = (const float*)d_in[10];
    const float* Wo = (const float*)d_in[11];
    const float* bo = (const float*)d_in[12];

    short* S = (short*)d_ws;
    const long NE = 2097152;             // 4096*512 elements
    short* WSp = S;                      // 5 * 524288 shorts
    short* Qh  = S + 2621440;
    short* Ql  = Qh + NE;
    short* Kh  = Ql + NE;
    short* Kl  = Kh + NE;
    short* Vth = Kl + NE;
    short* Vtl = Vth + NE;
    float* G   = (float*)(Vtl + NE);     // NE floats
    short* RGh = (short*)(G + NE);
    short* RGl = RGh + NE;

    wsplit_kernel<<<320, 256, 0, stream>>>(Wq, Wk, Wv, Wg, Wo, WSp);
    projqkvg_kernel<<<dim3(4, 32, 4), 256, 0, stream>>>(
        query, kin, vin, WSp, bq, bk, bv, bg,
        Qh, Ql, Kh, Kl, Vth, Vtl, G);
    attn_kernel<<<dim3(32, 16), 256, 0, stream>>>(
        Qh, Ql, Kh, Kl, Vth, Vtl, G, RGh, RGl);
    projo_kernel<<<dim3(4, 64), 256, 0, stream>>>(
        RGh, RGl, WSp + 4 * 524288, bo, (float*)d_out);
}

// Round 6
// 318.742 us; speedup vs baseline: 2.3357x; 1.0397x over previous
//
#include <hip/hip_runtime.h>
#include <math.h>

typedef float f32x4 __attribute__((ext_vector_type(4)));
typedef short s16x8 __attribute__((ext_vector_type(8)));
typedef short s16x4 __attribute__((ext_vector_type(4)));

__device__ __forceinline__ short f2bf(float f) {
    unsigned u = __builtin_bit_cast(unsigned, f);
    unsigned r = u + 0x7FFFu + ((u >> 16) & 1u);
    return (short)(r >> 16);
}
__device__ __forceinline__ float bf2f(short h) {
    return __builtin_bit_cast(float, ((unsigned)(unsigned short)h) << 16);
}
__device__ __forceinline__ unsigned pack2(short a, short b) {
    return (unsigned)(unsigned short)a | ((unsigned)(unsigned short)b << 16);
}

// split 8 contiguous fp32 into hi/lo bf16 (one s16x8 each)
__device__ __forceinline__ void split8(const float* __restrict__ p,
                                       short* hi, short* lo) {
    f32x4 a0 = *(const f32x4*)(p);
    f32x4 a1 = *(const f32x4*)(p + 4);
    s16x8 h0, l0;
    #pragma unroll
    for (int i = 0; i < 4; ++i) {
        short h;
        h = f2bf(a0[i]); h0[i]     = h; l0[i]     = f2bf(a0[i] - bf2f(h));
        h = f2bf(a1[i]); h0[4 + i] = h; l0[4 + i] = f2bf(a1[i] - bf2f(h));
    }
    *(s16x8*)hi = h0;
    *(s16x8*)lo = l0;
}

__device__ __forceinline__ void split16(const float* __restrict__ p,
                                        short* hi, short* lo) {
    split8(p, hi, lo);
    split8(p + 8, hi + 8, lo + 8);
}

// ---------------------------------------------------------------------------
// Pre-split the 5 weight matrices into hi/lo bf16 planes.
// ---------------------------------------------------------------------------
__global__ __launch_bounds__(256) void wsplit_kernel(
    const float* __restrict__ W0, const float* __restrict__ W1,
    const float* __restrict__ W2, const float* __restrict__ W3,
    const float* __restrict__ W4, short* __restrict__ outbase)
{
    const int blk = blockIdx.x;          // 64 blocks per W
    const int w = blk >> 6;
    const int bi = blk & 63;
    const float* src = (w == 0) ? W0 : (w == 1) ? W1 : (w == 2) ? W2
                      : (w == 3) ? W3 : W4;
    short* hi = outbase + (long)w * 524288;
    short* lo = hi + 262144;
    const int idx = (bi * 256 + threadIdx.x) * 16;
    split16(src + idx, hi + idx, lo + idx);
}

// ---------------------------------------------------------------------------
// Fused Q/K/V/G projections, blockIdx.z = mode. 64x128 tile (m x n),
// 4 waves 2x2 (wave tile 32x64), BK=32. 1024 blocks total.
// mode 0: Q rotary -> split [B,H,N,D]; 1: K rotary*0.125 -> split [B,H,N,D];
// mode 2: V -> split TRANSPOSED [B,H,D,N]; 3: G silu -> fp32 [B,N,E]
// ---------------------------------------------------------------------------
__global__ __launch_bounds__(256) void projqkvg_kernel(
    const float* __restrict__ Xq, const float* __restrict__ Xk,
    const float* __restrict__ Xv, const short* __restrict__ Wsp,
    const float* __restrict__ bq, const float* __restrict__ bk,
    const float* __restrict__ bv, const float* __restrict__ bg,
    short* __restrict__ Qh, short* __restrict__ Ql,
    short* __restrict__ Kh, short* __restrict__ Kl,
    short* __restrict__ Vth, short* __restrict__ Vtl,
    float* __restrict__ G)
{
    __shared__ __align__(16) short SB[15360];   // 30 KB
    short* XhS = SB;            // 64*40
    short* XlS = SB + 2560;
    short* WhS = SB + 5120;     // 128*40
    short* WlS = SB + 10240;

    const int mode = blockIdx.z;
    const float* X = (mode == 1) ? Xk : (mode == 2) ? Xv : Xq;
    const short* Wh_g = Wsp + (long)mode * 524288;
    const short* Wl_g = Wh_g + 262144;
    const float* bias = (mode == 0) ? bq : (mode == 1) ? bk
                       : (mode == 2) ? bv : bg;

    const int t = threadIdx.x, lane = t & 63, wv = t >> 6;
    const int wm = wv >> 1, wn = wv & 1;
    const int quad = lane >> 4, l15 = lane & 15;
    const int m0 = blockIdx.y * 64, n0 = blockIdx.x * 128;

    f32x4 acc[2][4];
    #pragma unroll
    for (int i = 0; i < 2; ++i)
        #pragma unroll
        for (int j = 0; j < 4; ++j)
            acc[i][j] = (f32x4){0.f, 0.f, 0.f, 0.f};

    const int xrow = t >> 2, xcol = (t & 3) * 8;
    const int wrow = t >> 1, wcol = (t & 1) * 16;

    for (int k0 = 0; k0 < 512; k0 += 32) {
        __syncthreads();
        split8(X + (long)(m0 + xrow) * 512 + k0 + xcol,
               &XhS[xrow * 40 + xcol], &XlS[xrow * 40 + xcol]);
        {
            const long wo = (long)(n0 + wrow) * 512 + k0 + wcol;
            s16x8 w0 = *(const s16x8*)(Wh_g + wo);
            s16x8 w1 = *(const s16x8*)(Wh_g + wo + 8);
            s16x8 w2 = *(const s16x8*)(Wl_g + wo);
            s16x8 w3 = *(const s16x8*)(Wl_g + wo + 8);
            *(s16x8*)&WhS[wrow * 40 + wcol]     = w0;
            *(s16x8*)&WhS[wrow * 40 + wcol + 8] = w1;
            *(s16x8*)&WlS[wrow * 40 + wcol]     = w2;
            *(s16x8*)&WlS[wrow * 40 + wcol + 8] = w3;
        }
        __syncthreads();

        s16x8 ah[2], al[2], bh[4], bl[4];
        #pragma unroll
        for (int s = 0; s < 2; ++s) {
            const int ro = (wm * 32 + s * 16 + l15) * 40 + quad * 8;
            ah[s] = *(const s16x8*)&XhS[ro];
            al[s] = *(const s16x8*)&XlS[ro];
        }
        #pragma unroll
        for (int s = 0; s < 4; ++s) {
            const int ro = (wn * 64 + s * 16 + l15) * 40 + quad * 8;
            bh[s] = *(const s16x8*)&WhS[ro];
            bl[s] = *(const s16x8*)&WlS[ro];
        }
        #pragma unroll
        for (int i = 0; i < 2; ++i)
            #pragma unroll
            for (int j = 0; j < 4; ++j) {
                acc[i][j] = __builtin_amdgcn_mfma_f32_16x16x32_bf16(ah[i], bh[j], acc[i][j], 0, 0, 0);
                acc[i][j] = __builtin_amdgcn_mfma_f32_16x16x32_bf16(al[i], bh[j], acc[i][j], 0, 0, 0);
                acc[i][j] = __builtin_amdgcn_mfma_f32_16x16x32_bf16(ah[i], bl[j], acc[i][j], 0, 0, 0);
            }
    }

    __syncthreads();   // staging reads done; LDS reusable

    const int bb = m0 >> 11, posb = m0 & 2047;

    if (mode <= 1) {
        short* Thi = SB + wv * 2304;    // 16 x 72 hi
        short* Tlo = Thi + 1152;
        short* OH = (mode == 0) ? Qh : Kh;
        short* OL = (mode == 0) ? Ql : Kl;
        const int hcol = (n0 >> 6) + wn;
        #pragma unroll
        for (int ms = 0; ms < 2; ++ms) {
            #pragma unroll
            for (int ns = 0; ns < 4; ++ns) {
                const int col = n0 + wn * 64 + ns * 16 + l15;
                const float bvv = bias[col];
                const int pp = (col & 63) >> 1;
                const float theta = powf(10000.0f, -(float)pp * (1.0f / 31.0f));
                #pragma unroll
                for (int r = 0; r < 4; ++r) {
                    const int m = m0 + wm * 32 + ms * 16 + quad * 4 + r;
                    const int pos = m & 2047;
                    float x = acc[ms][ns][r] + bvv;
                    float prt = __shfl_xor(x, 1);
                    float ang = (float)pos * theta;
                    float sv = sinf(ang), cv = cosf(ang);
                    float y0 = x * cv - prt * sv;
                    float y1 = prt * cv + x * sv;
                    if (mode == 1) { y0 *= 0.125f; y1 *= 0.125f; }
                    if (!(l15 & 1)) {
                        short h0 = f2bf(y0), h1 = f2bf(y1);
                        short l0 = f2bf(y0 - bf2f(h0)), l1 = f2bf(y1 - bf2f(h1));
                        const int o = (quad * 4 + r) * 72 + ns * 16 + l15;
                        *(unsigned*)&Thi[o] = pack2(h0, h1);
                        *(unsigned*)&Tlo[o] = pack2(l0, l1);
                    }
                }
            }
            const int mrow = wm * 32 + ms * 16;
            #pragma unroll
            for (int p2 = 0; p2 < 2; ++p2) {
                const int row = p2 * 8 + (lane >> 3);
                const int ch = (lane & 7) * 8;
                s16x8 vh = *(const s16x8*)&Thi[row * 72 + ch];
                s16x8 vl = *(const s16x8*)&Tlo[row * 72 + ch];
                const long o = ((long)(bb * 8 + hcol) * 2048 + posb + mrow + row) * 64 + ch;
                *(s16x8*)(OH + o) = vh;
                *(s16x8*)(OL + o) = vl;
            }
        }
    } else if (mode == 2) {
        // cooperative transposed store: T2[(head(wn)*64 + d)][token 0..63], stride 72
        short* T2 = SB;   // 128 x 72 = 9216 shorts
        #pragma unroll
        for (int pl = 0; pl < 2; ++pl) {
            if (pl) __syncthreads();
            #pragma unroll
            for (int ns = 0; ns < 4; ++ns) {
                const int col = n0 + wn * 64 + ns * 16 + l15;
                const float bvv = bias[col];
                #pragma unroll
                for (int ms = 0; ms < 2; ++ms) {
                    s16x4 pk;
                    #pragma unroll
                    for (int r = 0; r < 4; ++r) {
                        float x = acc[ms][ns][r] + bvv;
                        short hb = f2bf(x);
                        pk[r] = pl ? f2bf(x - bf2f(hb)) : hb;
                    }
                    *(s16x4*)&T2[(wn * 64 + ns * 16 + l15) * 72
                                 + wm * 32 + ms * 16 + quad * 4] = pk;
                }
            }
            __syncthreads();
            short* dst = pl ? Vtl : Vth;
            #pragma unroll
            for (int pass = 0; pass < 4; ++pass) {
                const int row = pass * 32 + (t >> 3);    // 0..127
                const int ch = (t & 7) * 8;
                s16x8 v = *(const s16x8*)&T2[row * 72 + ch];
                const int head = (n0 >> 6) + (row >> 6);
                const int d = row & 63;
                const long o = ((long)(bb * 8 + head) * 64 + d) * 2048 + posb + ch;
                *(s16x8*)(dst + o) = v;
            }
        }
    } else {
        #pragma unroll
        for (int ns = 0; ns < 4; ++ns) {
            const int col = n0 + wn * 64 + ns * 16 + l15;
            const float bvv = bias[col];
            #pragma unroll
            for (int ms = 0; ms < 2; ++ms)
                #pragma unroll
                for (int r = 0; r < 4; ++r) {
                    const int m = m0 + wm * 32 + ms * 16 + quad * 4 + r;
                    float x = acc[ms][ns][r] + bvv;
                    G[(long)m * 512 + col] = x / (1.0f + expf(-x));
                }
        }
    }
}

// ---------------------------------------------------------------------------
// Retention attention, split-bf16 MFMA, pre-split inputs, decay-cutoff
// tile skipping (gamma^(n-s) < 1e-5 -> tile dropped; contribution < 3e-4).
// ---------------------------------------------------------------------------
__global__ __launch_bounds__(256) void attn_kernel(
    const short* __restrict__ Qh_g, const short* __restrict__ Ql_g,
    const short* __restrict__ Kh_g, const short* __restrict__ Kl_g,
    const short* __restrict__ Vth_g, const short* __restrict__ Vtl_g,
    const float* __restrict__ G,
    short* __restrict__ RGh, short* __restrict__ RGl)
{
    __shared__ __align__(16) short KhS[64 * 72], KlS[64 * 72];
    __shared__ __align__(16) short VhS[64 * 72], VlS[64 * 72];
    __shared__ __align__(16) short PhS[64 * 68], PlS[64 * 68];

    const int t = threadIdx.x, lane = t & 63, wv = t >> 6;
    const int quad = lane >> 4, l15 = lane & 15;
    const int bh = blockIdx.y, h = bh & 7, b = bh >> 3;
    const int qt = (bh & 1) ? blockIdx.x : (31 - blockIdx.x);
    const int n0 = qt * 64;
    const long base = (long)bh * 2048 * 64;

    float l2g;
    int stLo;
    {
        float lg0 = logf(1.0f / 32.0f), lg1 = logf(1.0f / 512.0f);
        float om = expf(lg0 + (float)h * (lg1 - lg0) * (1.0f / 7.0f));  // 1-gamma
        l2g = log2f(1.0f - om);
        int Dcut = (int)(11.5129255f / om) + 64;   // ln(1e5)/(1-g) approx
        stLo = (n0 - Dcut) >> 6;
        if (stLo < 0) stLo = 0;
    }
    float gneg[16];
    #pragma unroll
    for (int i = 0; i < 16; ++i)
        gneg[i] = exp2f(-(float)((i >> 2) * 16 + (i & 3)) * l2g);

    const int srow = t >> 2;
    const int scol = (t & 3) * 16;
    const int n = n0 + wv * 16 + l15;

    s16x8 qh[2], ql[2];
    {
        const short* qp  = Qh_g + base + (long)(n0 + wv * 16 + l15) * 64 + quad * 8;
        const short* qp2 = Ql_g + base + (long)(n0 + wv * 16 + l15) * 64 + quad * 8;
        qh[0] = *(const s16x8*)qp;
        qh[1] = *(const s16x8*)(qp + 32);
        ql[0] = *(const s16x8*)qp2;
        ql[1] = *(const s16x8*)(qp2 + 32);
    }

    f32x4 racc[4];
    #pragma unroll
    for (int i = 0; i < 4; ++i) racc[i] = (f32x4){0.f, 0.f, 0.f, 0.f};

    for (int st = stLo; st <= qt; ++st) {
        const int s0 = st * 64;
        __syncthreads();
        {
            const long ko = base + (long)(s0 + srow) * 64 + scol;
            s16x8 a0 = *(const s16x8*)(Kh_g + ko);
            s16x8 a1 = *(const s16x8*)(Kh_g + ko + 8);
            s16x8 a2 = *(const s16x8*)(Kl_g + ko);
            s16x8 a3 = *(const s16x8*)(Kl_g + ko + 8);
            *(s16x8*)&KhS[srow * 72 + scol]     = a0;
            *(s16x8*)&KhS[srow * 72 + scol + 8] = a1;
            *(s16x8*)&KlS[srow * 72 + scol]     = a2;
            *(s16x8*)&KlS[srow * 72 + scol + 8] = a3;

            const long vo = base + (long)srow * 2048 + s0 + scol;
            s16x8 b0 = *(const s16x8*)(Vth_g + vo);
            s16x8 b1 = *(const s16x8*)(Vth_g + vo + 8);
            s16x8 b2 = *(const s16x8*)(Vtl_g + vo);
            s16x8 b3 = *(const s16x8*)(Vtl_g + vo + 8);
            *(s16x8*)&VhS[srow * 72 + scol]     = b0;
            *(s16x8*)&VhS[srow * 72 + scol + 8] = b1;
            *(s16x8*)&VlS[srow * 72 + scol]     = b2;
            *(s16x8*)&VlS[srow * 72 + scol + 8] = b3;
        }
        __syncthreads();

        const float t0 = exp2f((float)(n - s0 - quad * 4) * l2g);

        #pragma unroll
        for (int sub = 0; sub < 4; ++sub) {
            const int ro = (sub * 16 + l15) * 72 + quad * 8;
            s16x8 kh0 = *(const s16x8*)&KhS[ro];
            s16x8 kh1 = *(const s16x8*)&KhS[ro + 32];
            s16x8 kl0 = *(const s16x8*)&KlS[ro];
            s16x8 kl1 = *(const s16x8*)&KlS[ro + 32];
            f32x4 sacc = (f32x4){0.f, 0.f, 0.f, 0.f};
            sacc = __builtin_amdgcn_mfma_f32_16x16x32_bf16(kh0, qh[0], sacc, 0, 0, 0);
            sacc = __builtin_amdgcn_mfma_f32_16x16x32_bf16(kh1, qh[1], sacc, 0, 0, 0);
            sacc = __builtin_amdgcn_mfma_f32_16x16x32_bf16(kl0, qh[0], sacc, 0, 0, 0);
            sacc = __builtin_amdgcn_mfma_f32_16x16x32_bf16(kl1, qh[1], sacc, 0, 0, 0);
            sacc = __builtin_amdgcn_mfma_f32_16x16x32_bf16(kh0, ql[0], sacc, 0, 0, 0);
            sacc = __builtin_amdgcn_mfma_f32_16x16x32_bf16(kh1, ql[1], sacc, 0, 0, 0);

            const int sb = s0 + sub * 16 + quad * 4;
            s16x4 pkh, pkl;
            #pragma unroll
            for (int r = 0; r < 4; ++r) {
                const int s = sb + r;
                const float wgt = (n >= s) ? t0 * gneg[sub * 4 + r] : 0.0f;
                const float p = sacc[r] * wgt;
                short hb = f2bf(p);
                pkh[r] = hb;
                pkl[r] = f2bf(p - bf2f(hb));
            }
            const int po = (wv * 16 + l15) * 68 + sub * 16 + quad * 4;
            *(s16x4*)&PhS[po] = pkh;
            *(s16x4*)&PlS[po] = pkl;
        }

        const int pro = (wv * 16 + l15) * 68 + quad * 8;
        s16x8 ph0 = *(const s16x8*)&PhS[pro];
        s16x8 ph1 = *(const s16x8*)&PhS[pro + 32];
        s16x8 pl0 = *(const s16x8*)&PlS[pro];
        s16x8 pl1 = *(const s16x8*)&PlS[pro + 32];
        #pragma unroll
        for (int ds = 0; ds < 4; ++ds) {
            const int ro = (ds * 16 + l15) * 72 + quad * 8;
            s16x8 vh0 = *(const s16x8*)&VhS[ro];
            s16x8 vh1 = *(const s16x8*)&VhS[ro + 32];
            s16x8 vl0 = *(const s16x8*)&VlS[ro];
            s16x8 vl1 = *(const s16x8*)&VlS[ro + 32];
            racc[ds] = __builtin_amdgcn_mfma_f32_16x16x32_bf16(ph0, vh0, racc[ds], 0, 0, 0);
            racc[ds] = __builtin_amdgcn_mfma_f32_16x16x32_bf16(ph1, vh1, racc[ds], 0, 0, 0);
            racc[ds] = __builtin_amdgcn_mfma_f32_16x16x32_bf16(pl0, vh0, racc[ds], 0, 0, 0);
            racc[ds] = __builtin_amdgcn_mfma_f32_16x16x32_bf16(pl1, vh1, racc[ds], 0, 0, 0);
            racc[ds] = __builtin_amdgcn_mfma_f32_16x16x32_bf16(ph0, vl0, racc[ds], 0, 0, 0);
            racc[ds] = __builtin_amdgcn_mfma_f32_16x16x32_bf16(ph1, vl1, racc[ds], 0, 0, 0);
        }
    }

    float mean[4], rstd[4];
    #pragma unroll
    for (int r = 0; r < 4; ++r) {
        float s = racc[0][r] + racc[1][r] + racc[2][r] + racc[3][r];
        s += __shfl_xor(s, 1); s += __shfl_xor(s, 2);
        s += __shfl_xor(s, 4); s += __shfl_xor(s, 8);
        mean[r] = s * (1.0f / 64.0f);
        float vs = 0.f;
        #pragma unroll
        for (int ds = 0; ds < 4; ++ds) {
            float d = racc[ds][r] - mean[r];
            vs += d * d;
        }
        vs += __shfl_xor(vs, 1); vs += __shfl_xor(vs, 2);
        vs += __shfl_xor(vs, 4); vs += __shfl_xor(vs, 8);
        rstd[r] = rsqrtf(vs * (1.0f / 64.0f) + 1e-6f);
    }

    __syncthreads();
    short* rgH = KhS + wv * 1152;
    short* rgL = KlS + wv * 1152;
    #pragma unroll
    for (int ds = 0; ds < 4; ++ds) {
        #pragma unroll
        for (int r = 0; r < 4; ++r) {
            const int nn = n0 + wv * 16 + quad * 4 + r;
            const int d = ds * 16 + l15;
            const long gi = ((long)(b * 2048 + nn)) * 512 + h * 64 + d;
            float rg = (racc[ds][r] - mean[r]) * rstd[r] * G[gi];
            float prt = __shfl_xor(rg, 1);
            if (!(l15 & 1)) {
                short h0 = f2bf(rg), h1 = f2bf(prt);
                short l0 = f2bf(rg - bf2f(h0)), l1 = f2bf(prt - bf2f(h1));
                const int o = (quad * 4 + r) * 72 + ds * 16 + l15;
                *(unsigned*)&rgH[o] = pack2(h0, h1);
                *(unsigned*)&rgL[o] = pack2(l0, l1);
            }
        }
    }
    #pragma unroll
    for (int p2 = 0; p2 < 2; ++p2) {
        const int row = p2 * 8 + (lane >> 3);
        const int ch = (lane & 7) * 8;
        s16x8 vh = *(const s16x8*)&rgH[row * 72 + ch];
        s16x8 vl = *(const s16x8*)&rgL[row * 72 + ch];
        const int nn = n0 + wv * 16 + row;
        const long o = ((long)(b * 2048 + nn)) * 512 + h * 64 + ch;
        *(s16x8*)(RGh + o) = vh;
        *(s16x8*)(RGl + o) = vl;
    }
}

// ---------------------------------------------------------------------------
// Output projection: out = RG @ Wo^T + bo. 32x128 tile, waves 2x2 (16x64).
// 512 blocks. fp32 output LDS-assembled for coalescing.
// ---------------------------------------------------------------------------
__global__ __launch_bounds__(256) void projo_kernel(
    const short* __restrict__ RGh, const short* __restrict__ RGl,
    const short* __restrict__ Woh_g, const float* __restrict__ bo,
    float* __restrict__ out)
{
    __shared__ __align__(16) char PB[25600];
    short* XhS = (short*)PB;            // 32*40
    short* XlS = XhS + 1280;
    short* WhS = XhS + 2560;            // 128*40
    short* WlS = XhS + 7680;

    const short* Wol_g = Woh_g + 262144;
    const int t = threadIdx.x, lane = t & 63, wv = t >> 6;
    const int wm = wv >> 1, wn = wv & 1;
    const int quad = lane >> 4, l15 = lane & 15;
    const int m0 = blockIdx.y * 32, n0 = blockIdx.x * 128;

    f32x4 acc[4];
    #pragma unroll
    for (int j = 0; j < 4; ++j) acc[j] = (f32x4){0.f, 0.f, 0.f, 0.f};

    const int xrow = t >> 3, xcol = (t & 7) * 4;
    const int wrow = t >> 1, wcol = (t & 1) * 16;

    for (int k0 = 0; k0 < 512; k0 += 32) {
        __syncthreads();
        {
            const long xo = (long)(m0 + xrow) * 512 + k0 + xcol;
            *(s16x4*)&XhS[xrow * 40 + xcol] = *(const s16x4*)(RGh + xo);
            *(s16x4*)&XlS[xrow * 40 + xcol] = *(const s16x4*)(RGl + xo);

            const long wo = (long)(n0 + wrow) * 512 + k0 + wcol;
            s16x8 w0 = *(const s16x8*)(Woh_g + wo);
            s16x8 w1 = *(const s16x8*)(Woh_g + wo + 8);
            s16x8 w2 = *(const s16x8*)(Wol_g + wo);
            s16x8 w3 = *(const s16x8*)(Wol_g + wo + 8);
            *(s16x8*)&WhS[wrow * 40 + wcol]     = w0;
            *(s16x8*)&WhS[wrow * 40 + wcol + 8] = w1;
            *(s16x8*)&WlS[wrow * 40 + wcol]     = w2;
            *(s16x8*)&WlS[wrow * 40 + wcol + 8] = w3;
        }
        __syncthreads();

        s16x8 ah, al, bh[4], bl[4];
        {
            const int ro = (wm * 16 + l15) * 40 + quad * 8;
            ah = *(const s16x8*)&XhS[ro];
            al = *(const s16x8*)&XlS[ro];
        }
        #pragma unroll
        for (int s = 0; s < 4; ++s) {
            const int ro = (wn * 64 + s * 16 + l15) * 40 + quad * 8;
            bh[s] = *(const s16x8*)&WhS[ro];
            bl[s] = *(const s16x8*)&WlS[ro];
        }
        #pragma unroll
        for (int j = 0; j < 4; ++j) {
            acc[j] = __builtin_amdgcn_mfma_f32_16x16x32_bf16(ah, bh[j], acc[j], 0, 0, 0);
            acc[j] = __builtin_amdgcn_mfma_f32_16x16x32_bf16(al, bh[j], acc[j], 0, 0, 0);
            acc[j] = __builtin_amdgcn_mfma_f32_16x16x32_bf16(ah, bl[j], acc[j], 0, 0, 0);
        }
    }

    __syncthreads();
    float* T = (float*)PB + wv * 1152;   // 16 x 72 fp32
    #pragma unroll
    for (int ns = 0; ns < 4; ++ns) {
        const int col = n0 + wn * 64 + ns * 16 + l15;
        const float bvv = bo[col];
        #pragma unroll
        for (int r = 0; r < 4; ++r)
            T[(quad * 4 + r) * 72 + ns * 16 + l15] = acc[ns][r] + bvv;
    }
    #pragma unroll
    for (int it = 0; it < 2; ++it) {
        const int row = it * 8 + (lane >> 3);
        const int ch = (lane & 7) * 8;
        f32x4 a = *(const f32x4*)&T[row * 72 + ch];
        f32x4 c = *(const f32x4*)&T[row * 72 + ch + 4];
        const long o = (long)(m0 + wm * 16 + row) * 512 + n0 + wn * 64 + ch;
        *(f32x4*)(out + o) = a;
        *(f32x4*)(out + o + 4) = c;
    }
}

extern "C" void kernel_launch(void* const* d_in, const int* in_sizes, int n_in,
                              void* d_out, int out_size, void* d_ws, size_t ws_size,
                              hipStream_t stream) {
    const float* query = (const float*)d_in[0];
    const float* kin   = (const float*)d_in[1];
    const float* vin   = (const float*)d_in[2];
    const float* Wq = (const float*)d_in[3];
    const float* bq = (const float*)d_in[4];
    const float* Wk = (const float*)d_in[5];
    const float* bk = (const float*)d_in[6];
    const float* Wv = (const float*)d_in[7];
    const float* bv = (const float*)d_in[8];
    const float* Wg = (const float*)d_in[9];
    const float* bg = (const float*)d_in[10];
    const float* Wo = (const float*)d_in[11];
    const float* bo = (const float*)d_in[12];

    short* S = (short*)d_ws;
    const long NE = 2097152;             // 4096*512 elements
    short* WSp = S;                      // 5 * 524288 shorts
    short* Qh  = S + 2621440;
    short* Ql  = Qh + NE;
    short* Kh  = Ql + NE;
    short* Kl  = Kh + NE;
    short* Vth = Kl + NE;
    short* Vtl = Vth + NE;
    float* G   = (float*)(Vtl + NE);     // NE floats
    short* RGh = (short*)(G + NE);
    short* RGl = RGh + NE;

    wsplit_kernel<<<320, 256, 0, stream>>>(Wq, Wk, Wv, Wg, Wo, WSp);
    projqkvg_kernel<<<dim3(4, 64, 4), 256, 0, stream>>>(
        query, kin, vin, WSp, bq, bk, bv, bg,
        Qh, Ql, Kh, Kl, Vth, Vtl, G);
    attn_kernel<<<dim3(32, 16), 256, 0, stream>>>(
        Qh, Ql, Kh, Kl, Vth, Vtl, G, RGh, RGl);
    projo_kernel<<<dim3(4, 128), 256, 0, stream>>>(
        RGh, RGl, WSp + 4 * 524288, bo, (float*)d_out);
}

// Round 7
// 297.781 us; speedup vs baseline: 2.5001x; 1.0704x over previous
//
#include <hip/hip_runtime.h>
#include <math.h>

typedef float f32x4 __attribute__((ext_vector_type(4)));
typedef short s16x8 __attribute__((ext_vector_type(8)));
typedef short s16x4 __attribute__((ext_vector_type(4)));

__device__ __forceinline__ short f2bf(float f) {
    unsigned u = __builtin_bit_cast(unsigned, f);
    unsigned r = u + 0x7FFFu + ((u >> 16) & 1u);
    return (short)(r >> 16);
}
__device__ __forceinline__ float bf2f(short h) {
    return __builtin_bit_cast(float, ((unsigned)(unsigned short)h) << 16);
}
__device__ __forceinline__ unsigned pack2(short a, short b) {
    return (unsigned)(unsigned short)a | ((unsigned)(unsigned short)b << 16);
}

__device__ __forceinline__ void split16(const float* __restrict__ p,
                                        short* hi, short* lo) {
    f32x4 a0 = *(const f32x4*)(p);
    f32x4 a1 = *(const f32x4*)(p + 4);
    f32x4 a2 = *(const f32x4*)(p + 8);
    f32x4 a3 = *(const f32x4*)(p + 12);
    s16x8 h0, h1, l0, l1;
    #pragma unroll
    for (int i = 0; i < 4; ++i) {
        short h;
        h = f2bf(a0[i]); h0[i]     = h; l0[i]     = f2bf(a0[i] - bf2f(h));
        h = f2bf(a1[i]); h0[4 + i] = h; l0[4 + i] = f2bf(a1[i] - bf2f(h));
        h = f2bf(a2[i]); h1[i]     = h; l1[i]     = f2bf(a2[i] - bf2f(h));
        h = f2bf(a3[i]); h1[4 + i] = h; l1[4 + i] = f2bf(a3[i] - bf2f(h));
    }
    *(s16x8*)hi       = h0;
    *(s16x8*)(hi + 8) = h1;
    *(s16x8*)lo       = l0;
    *(s16x8*)(lo + 8) = l1;
}

// ---------------------------------------------------------------------------
// Pre-split 5 weight matrices AND the 3 activation inputs into hi/lo bf16.
// ---------------------------------------------------------------------------
__global__ __launch_bounds__(256) void presplit_kernel(
    const float* __restrict__ W0, const float* __restrict__ W1,
    const float* __restrict__ W2, const float* __restrict__ W3,
    const float* __restrict__ W4,
    const float* __restrict__ X0, const float* __restrict__ X1,
    const float* __restrict__ X2,
    short* __restrict__ Wsp, short* __restrict__ Xsp)
{
    const int blk = blockIdx.x;
    if (blk < 320) {
        const int w = blk >> 6, bi = blk & 63;
        const float* src = (w == 0) ? W0 : (w == 1) ? W1 : (w == 2) ? W2
                          : (w == 3) ? W3 : W4;
        short* hi = Wsp + (long)w * 524288;
        short* lo = hi + 262144;
        const int idx = (bi * 256 + threadIdx.x) * 16;
        split16(src + idx, hi + idx, lo + idx);
    } else {
        const int b2 = blk - 320;
        const int x = b2 >> 9, bi = b2 & 511;   // 512 blocks per X
        const float* src = (x == 0) ? X0 : (x == 1) ? X1 : X2;
        short* hi = Xsp + (long)x * 4194304;
        short* lo = hi + 2097152;
        const int idx = (bi * 256 + threadIdx.x) * 16;
        split16(src + idx, hi + idx, lo + idx);
    }
}

// ---------------------------------------------------------------------------
// Fused Q/K/V/G projections, blockIdx.z = mode. 64x128 tile, 4 waves 2x2,
// BK=32, all-bf16 staging with VGPR software prefetch (loads for k+1 issued
// before MFMA phase of k).
// mode 0: Q rotary -> split [B,H,N,D]; 1: K rotary*0.125 -> hi [B,H,N,D];
// mode 2: V -> hi TRANSPOSED [B,H,D,N]; 3: G silu -> fp32 [B,N,E]
// ---------------------------------------------------------------------------
__global__ __launch_bounds__(256) void projqkvg_kernel(
    const short* __restrict__ Xsp, const short* __restrict__ Wsp,
    const float* __restrict__ bq, const float* __restrict__ bk,
    const float* __restrict__ bv, const float* __restrict__ bg,
    short* __restrict__ Qh, short* __restrict__ Ql,
    short* __restrict__ Kh, short* __restrict__ Vth,
    float* __restrict__ G)
{
    __shared__ __align__(16) short SB[15360];   // 30 KB
    short* XhS = SB;            // 64*40
    short* XlS = SB + 2560;
    short* WhS = SB + 5120;     // 128*40
    short* WlS = SB + 10240;

    const int mode = blockIdx.z;
    const int xi = (mode == 1) ? 1 : (mode == 2) ? 2 : 0;
    const short* Xh_g = Xsp + (long)xi * 4194304;
    const short* Xl_g = Xh_g + 2097152;
    const short* Wh_g = Wsp + (long)mode * 524288;
    const short* Wl_g = Wh_g + 262144;
    const float* bias = (mode == 0) ? bq : (mode == 1) ? bk
                       : (mode == 2) ? bv : bg;

    const int t = threadIdx.x, lane = t & 63, wv = t >> 6;
    const int wm = wv >> 1, wn = wv & 1;
    const int quad = lane >> 4, l15 = lane & 15;
    const int m0 = blockIdx.y * 64, n0 = blockIdx.x * 128;

    f32x4 acc[2][4];
    #pragma unroll
    for (int i = 0; i < 2; ++i)
        #pragma unroll
        for (int j = 0; j < 4; ++j)
            acc[i][j] = (f32x4){0.f, 0.f, 0.f, 0.f};

    const int xrow = t >> 2, xcol = (t & 3) * 8;
    const int wrow = t >> 1, wcol = (t & 1) * 16;
    const long xbase = (long)(m0 + xrow) * 512 + xcol;
    const long wbase = (long)(n0 + wrow) * 512 + wcol;

    s16x8 pxh, pxl, pwh0, pwh1, pwl0, pwl1;
    // prologue prefetch k0=0
    pxh  = *(const s16x8*)(Xh_g + xbase);
    pxl  = *(const s16x8*)(Xl_g + xbase);
    pwh0 = *(const s16x8*)(Wh_g + wbase);
    pwh1 = *(const s16x8*)(Wh_g + wbase + 8);
    pwl0 = *(const s16x8*)(Wl_g + wbase);
    pwl1 = *(const s16x8*)(Wl_g + wbase + 8);

    for (int k0 = 0; k0 < 512; k0 += 32) {
        __syncthreads();
        *(s16x8*)&XhS[xrow * 40 + xcol]     = pxh;
        *(s16x8*)&XlS[xrow * 40 + xcol]     = pxl;
        *(s16x8*)&WhS[wrow * 40 + wcol]     = pwh0;
        *(s16x8*)&WhS[wrow * 40 + wcol + 8] = pwh1;
        *(s16x8*)&WlS[wrow * 40 + wcol]     = pwl0;
        *(s16x8*)&WlS[wrow * 40 + wcol + 8] = pwl1;
        __syncthreads();

        if (k0 + 32 < 512) {
            const long xo = xbase + k0 + 32;
            const long wo = wbase + k0 + 32;
            pxh  = *(const s16x8*)(Xh_g + xo);
            pxl  = *(const s16x8*)(Xl_g + xo);
            pwh0 = *(const s16x8*)(Wh_g + wo);
            pwh1 = *(const s16x8*)(Wh_g + wo + 8);
            pwl0 = *(const s16x8*)(Wl_g + wo);
            pwl1 = *(const s16x8*)(Wl_g + wo + 8);
        }

        s16x8 ah[2], al[2], bh[4], bl[4];
        #pragma unroll
        for (int s = 0; s < 2; ++s) {
            const int ro = (wm * 32 + s * 16 + l15) * 40 + quad * 8;
            ah[s] = *(const s16x8*)&XhS[ro];
            al[s] = *(const s16x8*)&XlS[ro];
        }
        #pragma unroll
        for (int s = 0; s < 4; ++s) {
            const int ro = (wn * 64 + s * 16 + l15) * 40 + quad * 8;
            bh[s] = *(const s16x8*)&WhS[ro];
            bl[s] = *(const s16x8*)&WlS[ro];
        }
        #pragma unroll
        for (int i = 0; i < 2; ++i)
            #pragma unroll
            for (int j = 0; j < 4; ++j) {
                acc[i][j] = __builtin_amdgcn_mfma_f32_16x16x32_bf16(ah[i], bh[j], acc[i][j], 0, 0, 0);
                acc[i][j] = __builtin_amdgcn_mfma_f32_16x16x32_bf16(al[i], bh[j], acc[i][j], 0, 0, 0);
                acc[i][j] = __builtin_amdgcn_mfma_f32_16x16x32_bf16(ah[i], bl[j], acc[i][j], 0, 0, 0);
            }
    }

    __syncthreads();   // staging reads done; LDS reusable

    const int bb = m0 >> 11, posb = m0 & 2047;

    if (mode == 0) {
        // Q: hi + lo planes
        short* Thi = SB + wv * 2304;
        short* Tlo = Thi + 1152;
        const int hcol = (n0 >> 6) + wn;
        #pragma unroll
        for (int ms = 0; ms < 2; ++ms) {
            #pragma unroll
            for (int ns = 0; ns < 4; ++ns) {
                const int col = n0 + wn * 64 + ns * 16 + l15;
                const float bvv = bias[col];
                const int pp = (col & 63) >> 1;
                const float theta = powf(10000.0f, -(float)pp * (1.0f / 31.0f));
                #pragma unroll
                for (int r = 0; r < 4; ++r) {
                    const int m = m0 + wm * 32 + ms * 16 + quad * 4 + r;
                    const int pos = m & 2047;
                    float x = acc[ms][ns][r] + bvv;
                    float prt = __shfl_xor(x, 1);
                    float ang = (float)pos * theta;
                    float sv = sinf(ang), cv = cosf(ang);
                    float y0 = x * cv - prt * sv;
                    float y1 = prt * cv + x * sv;
                    if (!(l15 & 1)) {
                        short h0 = f2bf(y0), h1 = f2bf(y1);
                        short l0 = f2bf(y0 - bf2f(h0)), l1 = f2bf(y1 - bf2f(h1));
                        const int o = (quad * 4 + r) * 72 + ns * 16 + l15;
                        *(unsigned*)&Thi[o] = pack2(h0, h1);
                        *(unsigned*)&Tlo[o] = pack2(l0, l1);
                    }
                }
            }
            const int mrow = wm * 32 + ms * 16;
            #pragma unroll
            for (int p2 = 0; p2 < 2; ++p2) {
                const int row = p2 * 8 + (lane >> 3);
                const int ch = (lane & 7) * 8;
                s16x8 vh = *(const s16x8*)&Thi[row * 72 + ch];
                s16x8 vl = *(const s16x8*)&Tlo[row * 72 + ch];
                const long o = ((long)(bb * 8 + hcol) * 2048 + posb + mrow + row) * 64 + ch;
                *(s16x8*)(Qh + o) = vh;
                *(s16x8*)(Ql + o) = vl;
            }
        }
    } else if (mode == 1) {
        // K: hi plane only (rotary * 0.125)
        short* Thi = SB + wv * 1152;
        const int hcol = (n0 >> 6) + wn;
        #pragma unroll
        for (int ms = 0; ms < 2; ++ms) {
            #pragma unroll
            for (int ns = 0; ns < 4; ++ns) {
                const int col = n0 + wn * 64 + ns * 16 + l15;
                const float bvv = bias[col];
                const int pp = (col & 63) >> 1;
                const float theta = powf(10000.0f, -(float)pp * (1.0f / 31.0f));
                #pragma unroll
                for (int r = 0; r < 4; ++r) {
                    const int m = m0 + wm * 32 + ms * 16 + quad * 4 + r;
                    const int pos = m & 2047;
                    float x = acc[ms][ns][r] + bvv;
                    float prt = __shfl_xor(x, 1);
                    float ang = (float)pos * theta;
                    float sv = sinf(ang), cv = cosf(ang);
                    float y0 = (x * cv - prt * sv) * 0.125f;
                    float y1 = (prt * cv + x * sv) * 0.125f;
                    if (!(l15 & 1)) {
                        const int o = (quad * 4 + r) * 72 + ns * 16 + l15;
                        *(unsigned*)&Thi[o] = pack2(f2bf(y0), f2bf(y1));
                    }
                }
            }
            const int mrow = wm * 32 + ms * 16;
            #pragma unroll
            for (int p2 = 0; p2 < 2; ++p2) {
                const int row = p2 * 8 + (lane >> 3);
                const int ch = (lane & 7) * 8;
                s16x8 vh = *(const s16x8*)&Thi[row * 72 + ch];
                const long o = ((long)(bb * 8 + hcol) * 2048 + posb + mrow + row) * 64 + ch;
                *(s16x8*)(Kh + o) = vh;
            }
        }
    } else if (mode == 2) {
        // V: hi only, transposed cooperative store
        short* T2 = SB;   // 128 x 72
        #pragma unroll
        for (int ns = 0; ns < 4; ++ns) {
            const int col = n0 + wn * 64 + ns * 16 + l15;
            const float bvv = bias[col];
            #pragma unroll
            for (int ms = 0; ms < 2; ++ms) {
                s16x4 pk;
                #pragma unroll
                for (int r = 0; r < 4; ++r)
                    pk[r] = f2bf(acc[ms][ns][r] + bvv);
                *(s16x4*)&T2[(wn * 64 + ns * 16 + l15) * 72
                             + wm * 32 + ms * 16 + quad * 4] = pk;
            }
        }
        __syncthreads();
        #pragma unroll
        for (int pass = 0; pass < 4; ++pass) {
            const int row = pass * 32 + (t >> 3);    // 0..127
            const int ch = (t & 7) * 8;
            s16x8 v = *(const s16x8*)&T2[row * 72 + ch];
            const int head = (n0 >> 6) + (row >> 6);
            const int d = row & 63;
            const long o = ((long)(bb * 8 + head) * 64 + d) * 2048 + posb + ch;
            *(s16x8*)(Vth + o) = v;
        }
    } else {
        #pragma unroll
        for (int ns = 0; ns < 4; ++ns) {
            const int col = n0 + wn * 64 + ns * 16 + l15;
            const float bvv = bias[col];
            #pragma unroll
            for (int ms = 0; ms < 2; ++ms)
                #pragma unroll
                for (int r = 0; r < 4; ++r) {
                    const int m = m0 + wm * 32 + ms * 16 + quad * 4 + r;
                    float x = acc[ms][ns][r] + bvv;
                    G[(long)m * 512 + col] = x / (1.0f + expf(-x));
                }
        }
    }
}

// ---------------------------------------------------------------------------
// Retention attention. K,V bf16 hi-only; Q and P split. Decay-cutoff tile
// skipping. RG output split hi/lo, LDS-assembled coalesced stores.
// ---------------------------------------------------------------------------
__global__ __launch_bounds__(256) void attn_kernel(
    const short* __restrict__ Qh_g, const short* __restrict__ Ql_g,
    const short* __restrict__ Kh_g, const short* __restrict__ Vth_g,
    const float* __restrict__ G,
    short* __restrict__ RGh, short* __restrict__ RGl)
{
    __shared__ __align__(16) short KhS[64 * 72], VhS[64 * 72];
    __shared__ __align__(16) short PhS[64 * 68], PlS[64 * 68];

    const int t = threadIdx.x, lane = t & 63, wv = t >> 6;
    const int quad = lane >> 4, l15 = lane & 15;
    const int bh = blockIdx.y, h = bh & 7, b = bh >> 3;
    const int qt = (bh & 1) ? blockIdx.x : (31 - blockIdx.x);
    const int n0 = qt * 64;
    const long base = (long)bh * 2048 * 64;

    float l2g;
    int stLo;
    {
        float lg0 = logf(1.0f / 32.0f), lg1 = logf(1.0f / 512.0f);
        float om = expf(lg0 + (float)h * (lg1 - lg0) * (1.0f / 7.0f));  // 1-gamma
        l2g = log2f(1.0f - om);
        int Dcut = (int)(11.5129255f / om) + 64;
        stLo = (n0 - Dcut) >> 6;
        if (stLo < 0) stLo = 0;
    }
    float gneg[16];
    #pragma unroll
    for (int i = 0; i < 16; ++i)
        gneg[i] = exp2f(-(float)((i >> 2) * 16 + (i & 3)) * l2g);

    const int srow = t >> 2;
    const int scol = (t & 3) * 16;
    const int n = n0 + wv * 16 + l15;

    s16x8 qh[2], ql[2];
    {
        const short* qp  = Qh_g + base + (long)(n0 + wv * 16 + l15) * 64 + quad * 8;
        const short* qp2 = Ql_g + base + (long)(n0 + wv * 16 + l15) * 64 + quad * 8;
        qh[0] = *(const s16x8*)qp;
        qh[1] = *(const s16x8*)(qp + 32);
        ql[0] = *(const s16x8*)qp2;
        ql[1] = *(const s16x8*)(qp2 + 32);
    }

    f32x4 racc[4];
    #pragma unroll
    for (int i = 0; i < 4; ++i) racc[i] = (f32x4){0.f, 0.f, 0.f, 0.f};

    for (int st = stLo; st <= qt; ++st) {
        const int s0 = st * 64;
        __syncthreads();
        {
            const long ko = base + (long)(s0 + srow) * 64 + scol;
            s16x8 a0 = *(const s16x8*)(Kh_g + ko);
            s16x8 a1 = *(const s16x8*)(Kh_g + ko + 8);
            *(s16x8*)&KhS[srow * 72 + scol]     = a0;
            *(s16x8*)&KhS[srow * 72 + scol + 8] = a1;

            const long vo = base + (long)srow * 2048 + s0 + scol;
            s16x8 b0 = *(const s16x8*)(Vth_g + vo);
            s16x8 b1 = *(const s16x8*)(Vth_g + vo + 8);
            *(s16x8*)&VhS[srow * 72 + scol]     = b0;
            *(s16x8*)&VhS[srow * 72 + scol + 8] = b1;
        }
        __syncthreads();

        const float t0 = exp2f((float)(n - s0 - quad * 4) * l2g);

        #pragma unroll
        for (int sub = 0; sub < 4; ++sub) {
            const int ro = (sub * 16 + l15) * 72 + quad * 8;
            s16x8 kh0 = *(const s16x8*)&KhS[ro];
            s16x8 kh1 = *(const s16x8*)&KhS[ro + 32];
            f32x4 sacc = (f32x4){0.f, 0.f, 0.f, 0.f};
            sacc = __builtin_amdgcn_mfma_f32_16x16x32_bf16(kh0, qh[0], sacc, 0, 0, 0);
            sacc = __builtin_amdgcn_mfma_f32_16x16x32_bf16(kh1, qh[1], sacc, 0, 0, 0);
            sacc = __builtin_amdgcn_mfma_f32_16x16x32_bf16(kh0, ql[0], sacc, 0, 0, 0);
            sacc = __builtin_amdgcn_mfma_f32_16x16x32_bf16(kh1, ql[1], sacc, 0, 0, 0);

            const int sb = s0 + sub * 16 + quad * 4;
            s16x4 pkh, pkl;
            #pragma unroll
            for (int r = 0; r < 4; ++r) {
                const int s = sb + r;
                const float wgt = (n >= s) ? t0 * gneg[sub * 4 + r] : 0.0f;
                const float p = sacc[r] * wgt;
                short hb = f2bf(p);
                pkh[r] = hb;
                pkl[r] = f2bf(p - bf2f(hb));
            }
            const int po = (wv * 16 + l15) * 68 + sub * 16 + quad * 4;
            *(s16x4*)&PhS[po] = pkh;
            *(s16x4*)&PlS[po] = pkl;
        }

        const int pro = (wv * 16 + l15) * 68 + quad * 8;
        s16x8 ph0 = *(const s16x8*)&PhS[pro];
        s16x8 ph1 = *(const s16x8*)&PhS[pro + 32];
        s16x8 pl0 = *(const s16x8*)&PlS[pro];
        s16x8 pl1 = *(const s16x8*)&PlS[pro + 32];
        #pragma unroll
        for (int ds = 0; ds < 4; ++ds) {
            const int ro = (ds * 16 + l15) * 72 + quad * 8;
            s16x8 vh0 = *(const s16x8*)&VhS[ro];
            s16x8 vh1 = *(const s16x8*)&VhS[ro + 32];
            racc[ds] = __builtin_amdgcn_mfma_f32_16x16x32_bf16(ph0, vh0, racc[ds], 0, 0, 0);
            racc[ds] = __builtin_amdgcn_mfma_f32_16x16x32_bf16(ph1, vh1, racc[ds], 0, 0, 0);
            racc[ds] = __builtin_amdgcn_mfma_f32_16x16x32_bf16(pl0, vh0, racc[ds], 0, 0, 0);
            racc[ds] = __builtin_amdgcn_mfma_f32_16x16x32_bf16(pl1, vh1, racc[ds], 0, 0, 0);
        }
    }

    float mean[4], rstd[4];
    #pragma unroll
    for (int r = 0; r < 4; ++r) {
        float s = racc[0][r] + racc[1][r] + racc[2][r] + racc[3][r];
        s += __shfl_xor(s, 1); s += __shfl_xor(s, 2);
        s += __shfl_xor(s, 4); s += __shfl_xor(s, 8);
        mean[r] = s * (1.0f / 64.0f);
        float vs = 0.f;
        #pragma unroll
        for (int ds = 0; ds < 4; ++ds) {
            float d = racc[ds][r] - mean[r];
            vs += d * d;
        }
        vs += __shfl_xor(vs, 1); vs += __shfl_xor(vs, 2);
        vs += __shfl_xor(vs, 4); vs += __shfl_xor(vs, 8);
        rstd[r] = rsqrtf(vs * (1.0f / 64.0f) + 1e-6f);
    }

    __syncthreads();
    short* rgH = KhS + wv * 1152;
    short* rgL = VhS + wv * 1152;
    #pragma unroll
    for (int ds = 0; ds < 4; ++ds) {
        #pragma unroll
        for (int r = 0; r < 4; ++r) {
            const int nn = n0 + wv * 16 + quad * 4 + r;
            const int d = ds * 16 + l15;
            const long gi = ((long)(b * 2048 + nn)) * 512 + h * 64 + d;
            float rg = (racc[ds][r] - mean[r]) * rstd[r] * G[gi];
            float prt = __shfl_xor(rg, 1);
            if (!(l15 & 1)) {
                short h0 = f2bf(rg), h1 = f2bf(prt);
                short l0 = f2bf(rg - bf2f(h0)), l1 = f2bf(prt - bf2f(h1));
                const int o = (quad * 4 + r) * 72 + ds * 16 + l15;
                *(unsigned*)&rgH[o] = pack2(h0, h1);
                *(unsigned*)&rgL[o] = pack2(l0, l1);
            }
        }
    }
    #pragma unroll
    for (int p2 = 0; p2 < 2; ++p2) {
        const int row = p2 * 8 + (lane >> 3);
        const int ch = (lane & 7) * 8;
        s16x8 vh = *(const s16x8*)&rgH[row * 72 + ch];
        s16x8 vl = *(const s16x8*)&rgL[row * 72 + ch];
        const int nn = n0 + wv * 16 + row;
        const long o = ((long)(b * 2048 + nn)) * 512 + h * 64 + ch;
        *(s16x8*)(RGh + o) = vh;
        *(s16x8*)(RGl + o) = vl;
    }
}

// ---------------------------------------------------------------------------
// Output projection: out = RG @ Wo^T + bo. 32x128 tile, waves 2x2 (16x64).
// ---------------------------------------------------------------------------
__global__ __launch_bounds__(256) void projo_kernel(
    const short* __restrict__ RGh, const short* __restrict__ RGl,
    const short* __restrict__ Woh_g, const float* __restrict__ bo,
    float* __restrict__ out)
{
    __shared__ __align__(16) char PB[25600];
    short* XhS = (short*)PB;            // 32*40
    short* XlS = XhS + 1280;
    short* WhS = XhS + 2560;            // 128*40
    short* WlS = XhS + 7680;

    const short* Wol_g = Woh_g + 262144;
    const int t = threadIdx.x, lane = t & 63, wv = t >> 6;
    const int wm = wv >> 1, wn = wv & 1;
    const int quad = lane >> 4, l15 = lane & 15;
    const int m0 = blockIdx.y * 32, n0 = blockIdx.x * 128;

    f32x4 acc[4];
    #pragma unroll
    for (int j = 0; j < 4; ++j) acc[j] = (f32x4){0.f, 0.f, 0.f, 0.f};

    const int xrow = t >> 3, xcol = (t & 7) * 4;
    const int wrow = t >> 1, wcol = (t & 1) * 16;

    for (int k0 = 0; k0 < 512; k0 += 32) {
        __syncthreads();
        {
            const long xo = (long)(m0 + xrow) * 512 + k0 + xcol;
            *(s16x4*)&XhS[xrow * 40 + xcol] = *(const s16x4*)(RGh + xo);
            *(s16x4*)&XlS[xrow * 40 + xcol] = *(const s16x4*)(RGl + xo);

            const long wo = (long)(n0 + wrow) * 512 + k0 + wcol;
            s16x8 w0 = *(const s16x8*)(Woh_g + wo);
            s16x8 w1 = *(const s16x8*)(Woh_g + wo + 8);
            s16x8 w2 = *(const s16x8*)(Wol_g + wo);
            s16x8 w3 = *(const s16x8*)(Wol_g + wo + 8);
            *(s16x8*)&WhS[wrow * 40 + wcol]     = w0;
            *(s16x8*)&WhS[wrow * 40 + wcol + 8] = w1;
            *(s16x8*)&WlS[wrow * 40 + wcol]     = w2;
            *(s16x8*)&WlS[wrow * 40 + wcol + 8] = w3;
        }
        __syncthreads();

        s16x8 ah, al, bh[4], bl[4];
        {
            const int ro = (wm * 16 + l15) * 40 + quad * 8;
            ah = *(const s16x8*)&XhS[ro];
            al = *(const s16x8*)&XlS[ro];
        }
        #pragma unroll
        for (int s = 0; s < 4; ++s) {
            const int ro = (wn * 64 + s * 16 + l15) * 40 + quad * 8;
            bh[s] = *(const s16x8*)&WhS[ro];
            bl[s] = *(const s16x8*)&WlS[ro];
        }
        #pragma unroll
        for (int j = 0; j < 4; ++j) {
            acc[j] = __builtin_amdgcn_mfma_f32_16x16x32_bf16(ah, bh[j], acc[j], 0, 0, 0);
            acc[j] = __builtin_amdgcn_mfma_f32_16x16x32_bf16(al, bh[j], acc[j], 0, 0, 0);
            acc[j] = __builtin_amdgcn_mfma_f32_16x16x32_bf16(ah, bl[j], acc[j], 0, 0, 0);
        }
    }

    __syncthreads();
    float* T = (float*)PB + wv * 1152;   // 16 x 72 fp32
    #pragma unroll
    for (int ns = 0; ns < 4; ++ns) {
        const int col = n0 + wn * 64 + ns * 16 + l15;
        const float bvv = bo[col];
        #pragma unroll
        for (int r = 0; r < 4; ++r)
            T[(quad * 4 + r) * 72 + ns * 16 + l15] = acc[ns][r] + bvv;
    }
    #pragma unroll
    for (int it = 0; it < 2; ++it) {
        const int row = it * 8 + (lane >> 3);
        const int ch = (lane & 7) * 8;
        f32x4 a = *(const f32x4*)&T[row * 72 + ch];
        f32x4 c = *(const f32x4*)&T[row * 72 + ch + 4];
        const long o = (long)(m0 + wm * 16 + row) * 512 + n0 + wn * 64 + ch;
        *(f32x4*)(out + o) = a;
        *(f32x4*)(out + o + 4) = c;
    }
}

extern "C" void kernel_launch(void* const* d_in, const int* in_sizes, int n_in,
                              void* d_out, int out_size, void* d_ws, size_t ws_size,
                              hipStream_t stream) {
    const float* query = (const float*)d_in[0];
    const float* kin   = (const float*)d_in[1];
    const float* vin   = (const float*)d_in[2];
    const float* Wq = (const float*)d_in[3];
    const float* bq = (const float*)d_in[4];
    const float* Wk = (const float*)d_in[5];
    const float* bk = (const float*)d_in[6];
    const float* Wv = (const float*)d_in[7];
    const float* bv = (const float*)d_in[8];
    const float* Wg = (const float*)d_in[9];
    const float* bg = (const float*)d_in[10];
    const float* Wo = (const float*)d_in[11];
    const float* bo = (const float*)d_in[12];

    short* S = (short*)d_ws;
    const long NE = 2097152;             // 4096*512 elements
    short* WSp = S;                      // 5 * 524288
    short* Xsp = S + 2621440;            // 3 * 4194304
    short* Qh  = Xsp + 12582912;
    short* Ql  = Qh + NE;
    short* Kh  = Ql + NE;
    short* Vth = Kh + NE;
    float* G   = (float*)(Vth + NE);     // NE floats
    short* RGh = (short*)(G + NE);
    short* RGl = RGh + NE;

    presplit_kernel<<<1856, 256, 0, stream>>>(
        Wq, Wk, Wv, Wg, Wo, query, kin, vin, WSp, Xsp);
    projqkvg_kernel<<<dim3(4, 64, 4), 256, 0, stream>>>(
        Xsp, WSp, bq, bk, bv, bg, Qh, Ql, Kh, Vth, G);
    attn_kernel<<<dim3(32, 16), 256, 0, stream>>>(
        Qh, Ql, Kh, Vth, G, RGh, RGl);
    projo_kernel<<<dim3(4, 128), 256, 0, stream>>>(
        RGh, RGl, WSp + 4 * 524288, bo, (float*)d_out);
}

// Round 8
// 268.172 us; speedup vs baseline: 2.7762x; 1.1104x over previous
//
#include <hip/hip_runtime.h>
#include <math.h>

typedef float f32x4 __attribute__((ext_vector_type(4)));
typedef short s16x8 __attribute__((ext_vector_type(8)));
typedef short s16x4 __attribute__((ext_vector_type(4)));

__device__ __forceinline__ short f2bf(float f) {
    unsigned u = __builtin_bit_cast(unsigned, f);
    unsigned r = u + 0x7FFFu + ((u >> 16) & 1u);
    return (short)(r >> 16);
}
__device__ __forceinline__ float bf2f(short h) {
    return __builtin_bit_cast(float, ((unsigned)(unsigned short)h) << 16);
}
__device__ __forceinline__ unsigned pack2(short a, short b) {
    return (unsigned)(unsigned short)a | ((unsigned)(unsigned short)b << 16);
}

__device__ __forceinline__ void split16(const float* __restrict__ p,
                                        short* hi, short* lo) {
    f32x4 a0 = *(const f32x4*)(p);
    f32x4 a1 = *(const f32x4*)(p + 4);
    f32x4 a2 = *(const f32x4*)(p + 8);
    f32x4 a3 = *(const f32x4*)(p + 12);
    s16x8 h0, h1, l0, l1;
    #pragma unroll
    for (int i = 0; i < 4; ++i) {
        short h;
        h = f2bf(a0[i]); h0[i]     = h; l0[i]     = f2bf(a0[i] - bf2f(h));
        h = f2bf(a1[i]); h0[4 + i] = h; l0[4 + i] = f2bf(a1[i] - bf2f(h));
        h = f2bf(a2[i]); h1[i]     = h; l1[i]     = f2bf(a2[i] - bf2f(h));
        h = f2bf(a3[i]); h1[4 + i] = h; l1[4 + i] = f2bf(a3[i] - bf2f(h));
    }
    *(s16x8*)hi       = h0;
    *(s16x8*)(hi + 8) = h1;
    *(s16x8*)lo       = l0;
    *(s16x8*)(lo + 8) = l1;
}

// ---------------------------------------------------------------------------
// Pre-split 5 weight matrices AND the 3 activation inputs into hi/lo bf16.
// ---------------------------------------------------------------------------
__global__ __launch_bounds__(256) void presplit_kernel(
    const float* __restrict__ W0, const float* __restrict__ W1,
    const float* __restrict__ W2, const float* __restrict__ W3,
    const float* __restrict__ W4,
    const float* __restrict__ X0, const float* __restrict__ X1,
    const float* __restrict__ X2,
    short* __restrict__ Wsp, short* __restrict__ Xsp)
{
    const int blk = blockIdx.x;
    if (blk < 320) {
        const int w = blk >> 6, bi = blk & 63;
        const float* src = (w == 0) ? W0 : (w == 1) ? W1 : (w == 2) ? W2
                          : (w == 3) ? W3 : W4;
        short* hi = Wsp + (long)w * 524288;
        short* lo = hi + 262144;
        const int idx = (bi * 256 + threadIdx.x) * 16;
        split16(src + idx, hi + idx, lo + idx);
    } else {
        const int b2 = blk - 320;
        const int x = b2 >> 9, bi = b2 & 511;   // 512 blocks per X
        const float* src = (x == 0) ? X0 : (x == 1) ? X1 : X2;
        short* hi = Xsp + (long)x * 4194304;
        short* lo = hi + 2097152;
        const int idx = (bi * 256 + threadIdx.x) * 16;
        split16(src + idx, hi + idx, lo + idx);
    }
}

// ---------------------------------------------------------------------------
// Fused Q/K/V/G projections, blockIdx.z = mode. 64x128 tile, 4 waves 2x2,
// BK=32, pre-split inputs, VGPR software prefetch.
// mode 0: Q rotary -> split [B,H,N,D]; 1: K rotary*0.125 -> hi [B,H,N,D];
// mode 2: V -> hi TRANSPOSED [B,H,D,N]; 3: G silu -> fp32 [B,N,E]
// ---------------------------------------------------------------------------
__global__ __launch_bounds__(256) void projqkvg_kernel(
    const short* __restrict__ Xsp, const short* __restrict__ Wsp,
    const float* __restrict__ bq, const float* __restrict__ bk,
    const float* __restrict__ bv, const float* __restrict__ bg,
    short* __restrict__ Qh, short* __restrict__ Ql,
    short* __restrict__ Kh, short* __restrict__ Vth,
    float* __restrict__ G)
{
    __shared__ __align__(16) short SB[15360];   // 30 KB
    short* XhS = SB;            // 64*40
    short* XlS = SB + 2560;
    short* WhS = SB + 5120;     // 128*40
    short* WlS = SB + 10240;

    const int mode = blockIdx.z;
    const int xi = (mode == 1) ? 1 : (mode == 2) ? 2 : 0;
    const short* Xh_g = Xsp + (long)xi * 4194304;
    const short* Xl_g = Xh_g + 2097152;
    const short* Wh_g = Wsp + (long)mode * 524288;
    const short* Wl_g = Wh_g + 262144;
    const float* bias = (mode == 0) ? bq : (mode == 1) ? bk
                       : (mode == 2) ? bv : bg;

    const int t = threadIdx.x, lane = t & 63, wv = t >> 6;
    const int wm = wv >> 1, wn = wv & 1;
    const int quad = lane >> 4, l15 = lane & 15;
    const int m0 = blockIdx.y * 64, n0 = blockIdx.x * 128;

    f32x4 acc[2][4];
    #pragma unroll
    for (int i = 0; i < 2; ++i)
        #pragma unroll
        for (int j = 0; j < 4; ++j)
            acc[i][j] = (f32x4){0.f, 0.f, 0.f, 0.f};

    const int xrow = t >> 2, xcol = (t & 3) * 8;
    const int wrow = t >> 1, wcol = (t & 1) * 16;
    const long xbase = (long)(m0 + xrow) * 512 + xcol;
    const long wbase = (long)(n0 + wrow) * 512 + wcol;

    s16x8 pxh, pxl, pwh0, pwh1, pwl0, pwl1;
    pxh  = *(const s16x8*)(Xh_g + xbase);
    pxl  = *(const s16x8*)(Xl_g + xbase);
    pwh0 = *(const s16x8*)(Wh_g + wbase);
    pwh1 = *(const s16x8*)(Wh_g + wbase + 8);
    pwl0 = *(const s16x8*)(Wl_g + wbase);
    pwl1 = *(const s16x8*)(Wl_g + wbase + 8);

    for (int k0 = 0; k0 < 512; k0 += 32) {
        __syncthreads();
        *(s16x8*)&XhS[xrow * 40 + xcol]     = pxh;
        *(s16x8*)&XlS[xrow * 40 + xcol]     = pxl;
        *(s16x8*)&WhS[wrow * 40 + wcol]     = pwh0;
        *(s16x8*)&WhS[wrow * 40 + wcol + 8] = pwh1;
        *(s16x8*)&WlS[wrow * 40 + wcol]     = pwl0;
        *(s16x8*)&WlS[wrow * 40 + wcol + 8] = pwl1;
        __syncthreads();

        if (k0 + 32 < 512) {
            const long xo = xbase + k0 + 32;
            const long wo = wbase + k0 + 32;
            pxh  = *(const s16x8*)(Xh_g + xo);
            pxl  = *(const s16x8*)(Xl_g + xo);
            pwh0 = *(const s16x8*)(Wh_g + wo);
            pwh1 = *(const s16x8*)(Wh_g + wo + 8);
            pwl0 = *(const s16x8*)(Wl_g + wo);
            pwl1 = *(const s16x8*)(Wl_g + wo + 8);
        }

        s16x8 ah[2], al[2], bh[4], bl[4];
        #pragma unroll
        for (int s = 0; s < 2; ++s) {
            const int ro = (wm * 32 + s * 16 + l15) * 40 + quad * 8;
            ah[s] = *(const s16x8*)&XhS[ro];
            al[s] = *(const s16x8*)&XlS[ro];
        }
        #pragma unroll
        for (int s = 0; s < 4; ++s) {
            const int ro = (wn * 64 + s * 16 + l15) * 40 + quad * 8;
            bh[s] = *(const s16x8*)&WhS[ro];
            bl[s] = *(const s16x8*)&WlS[ro];
        }
        #pragma unroll
        for (int i = 0; i < 2; ++i)
            #pragma unroll
            for (int j = 0; j < 4; ++j) {
                acc[i][j] = __builtin_amdgcn_mfma_f32_16x16x32_bf16(ah[i], bh[j], acc[i][j], 0, 0, 0);
                acc[i][j] = __builtin_amdgcn_mfma_f32_16x16x32_bf16(al[i], bh[j], acc[i][j], 0, 0, 0);
                acc[i][j] = __builtin_amdgcn_mfma_f32_16x16x32_bf16(ah[i], bl[j], acc[i][j], 0, 0, 0);
            }
    }

    __syncthreads();   // staging reads done; LDS reusable

    const int bb = m0 >> 11, posb = m0 & 2047;

    if (mode == 0) {
        short* Thi = SB + wv * 2304;
        short* Tlo = Thi + 1152;
        const int hcol = (n0 >> 6) + wn;
        #pragma unroll
        for (int ms = 0; ms < 2; ++ms) {
            #pragma unroll
            for (int ns = 0; ns < 4; ++ns) {
                const int col = n0 + wn * 64 + ns * 16 + l15;
                const float bvv = bias[col];
                const int pp = (col & 63) >> 1;
                const float theta = powf(10000.0f, -(float)pp * (1.0f / 31.0f));
                #pragma unroll
                for (int r = 0; r < 4; ++r) {
                    const int m = m0 + wm * 32 + ms * 16 + quad * 4 + r;
                    const int pos = m & 2047;
                    float x = acc[ms][ns][r] + bvv;
                    float prt = __shfl_xor(x, 1);
                    float ang = (float)pos * theta;
                    float sv = sinf(ang), cv = cosf(ang);
                    float y0 = x * cv - prt * sv;
                    float y1 = prt * cv + x * sv;
                    if (!(l15 & 1)) {
                        short h0 = f2bf(y0), h1 = f2bf(y1);
                        short l0 = f2bf(y0 - bf2f(h0)), l1 = f2bf(y1 - bf2f(h1));
                        const int o = (quad * 4 + r) * 72 + ns * 16 + l15;
                        *(unsigned*)&Thi[o] = pack2(h0, h1);
                        *(unsigned*)&Tlo[o] = pack2(l0, l1);
                    }
                }
            }
            const int mrow = wm * 32 + ms * 16;
            #pragma unroll
            for (int p2 = 0; p2 < 2; ++p2) {
                const int row = p2 * 8 + (lane >> 3);
                const int ch = (lane & 7) * 8;
                s16x8 vh = *(const s16x8*)&Thi[row * 72 + ch];
                s16x8 vl = *(const s16x8*)&Tlo[row * 72 + ch];
                const long o = ((long)(bb * 8 + hcol) * 2048 + posb + mrow + row) * 64 + ch;
                *(s16x8*)(Qh + o) = vh;
                *(s16x8*)(Ql + o) = vl;
            }
        }
    } else if (mode == 1) {
        short* Thi = SB + wv * 1152;
        const int hcol = (n0 >> 6) + wn;
        #pragma unroll
        for (int ms = 0; ms < 2; ++ms) {
            #pragma unroll
            for (int ns = 0; ns < 4; ++ns) {
                const int col = n0 + wn * 64 + ns * 16 + l15;
                const float bvv = bias[col];
                const int pp = (col & 63) >> 1;
                const float theta = powf(10000.0f, -(float)pp * (1.0f / 31.0f));
                #pragma unroll
                for (int r = 0; r < 4; ++r) {
                    const int m = m0 + wm * 32 + ms * 16 + quad * 4 + r;
                    const int pos = m & 2047;
                    float x = acc[ms][ns][r] + bvv;
                    float prt = __shfl_xor(x, 1);
                    float ang = (float)pos * theta;
                    float sv = sinf(ang), cv = cosf(ang);
                    float y0 = (x * cv - prt * sv) * 0.125f;
                    float y1 = (prt * cv + x * sv) * 0.125f;
                    if (!(l15 & 1)) {
                        const int o = (quad * 4 + r) * 72 + ns * 16 + l15;
                        *(unsigned*)&Thi[o] = pack2(f2bf(y0), f2bf(y1));
                    }
                }
            }
            const int mrow = wm * 32 + ms * 16;
            #pragma unroll
            for (int p2 = 0; p2 < 2; ++p2) {
                const int row = p2 * 8 + (lane >> 3);
                const int ch = (lane & 7) * 8;
                s16x8 vh = *(const s16x8*)&Thi[row * 72 + ch];
                const long o = ((long)(bb * 8 + hcol) * 2048 + posb + mrow + row) * 64 + ch;
                *(s16x8*)(Kh + o) = vh;
            }
        }
    } else if (mode == 2) {
        short* T2 = SB;   // 128 x 72
        #pragma unroll
        for (int ns = 0; ns < 4; ++ns) {
            const int col = n0 + wn * 64 + ns * 16 + l15;
            const float bvv = bias[col];
            #pragma unroll
            for (int ms = 0; ms < 2; ++ms) {
                s16x4 pk;
                #pragma unroll
                for (int r = 0; r < 4; ++r)
                    pk[r] = f2bf(acc[ms][ns][r] + bvv);
                *(s16x4*)&T2[(wn * 64 + ns * 16 + l15) * 72
                             + wm * 32 + ms * 16 + quad * 4] = pk;
            }
        }
        __syncthreads();
        #pragma unroll
        for (int pass = 0; pass < 4; ++pass) {
            const int row = pass * 32 + (t >> 3);    // 0..127
            const int ch = (t & 7) * 8;
            s16x8 v = *(const s16x8*)&T2[row * 72 + ch];
            const int head = (n0 >> 6) + (row >> 6);
            const int d = row & 63;
            const long o = ((long)(bb * 8 + head) * 64 + d) * 2048 + posb + ch;
            *(s16x8*)(Vth + o) = v;
        }
    } else {
        #pragma unroll
        for (int ns = 0; ns < 4; ++ns) {
            const int col = n0 + wn * 64 + ns * 16 + l15;
            const float bvv = bias[col];
            #pragma unroll
            for (int ms = 0; ms < 2; ++ms)
                #pragma unroll
                for (int r = 0; r < 4; ++r) {
                    const int m = m0 + wm * 32 + ms * 16 + quad * 4 + r;
                    float x = acc[ms][ns][r] + bvv;
                    G[(long)m * 512 + col] = x / (1.0f + expf(-x));
                }
        }
    }
}

// ---------------------------------------------------------------------------
// Retention attention. K,V,P bf16 hi-only; Q split. VGPR prefetch of next
// K/V tile. Decay-cutoff tile skipping. RG output single bf16 plane.
// ---------------------------------------------------------------------------
__global__ __launch_bounds__(256) void attn_kernel(
    const short* __restrict__ Qh_g, const short* __restrict__ Ql_g,
    const short* __restrict__ Kh_g, const short* __restrict__ Vth_g,
    const float* __restrict__ G,
    short* __restrict__ RGh)
{
    __shared__ __align__(16) short KhS[64 * 72], VhS[64 * 72];
    __shared__ __align__(16) short PhS[64 * 68];

    const int t = threadIdx.x, lane = t & 63, wv = t >> 6;
    const int quad = lane >> 4, l15 = lane & 15;
    const int bh = blockIdx.y, h = bh & 7, b = bh >> 3;
    const int qt = (bh & 1) ? blockIdx.x : (31 - blockIdx.x);
    const int n0 = qt * 64;
    const long base = (long)bh * 2048 * 64;

    float l2g;
    int stLo;
    {
        float lg0 = logf(1.0f / 32.0f), lg1 = logf(1.0f / 512.0f);
        float om = expf(lg0 + (float)h * (lg1 - lg0) * (1.0f / 7.0f));  // 1-gamma
        l2g = log2f(1.0f - om);
        int Dcut = (int)(11.5129255f / om) + 64;
        stLo = (n0 - Dcut) >> 6;
        if (stLo < 0) stLo = 0;
    }
    float gneg[16];
    #pragma unroll
    for (int i = 0; i < 16; ++i)
        gneg[i] = exp2f(-(float)((i >> 2) * 16 + (i & 3)) * l2g);

    const int srow = t >> 2;
    const int scol = (t & 3) * 16;
    const int n = n0 + wv * 16 + l15;

    s16x8 qh[2], ql[2];
    {
        const short* qp  = Qh_g + base + (long)(n0 + wv * 16 + l15) * 64 + quad * 8;
        const short* qp2 = Ql_g + base + (long)(n0 + wv * 16 + l15) * 64 + quad * 8;
        qh[0] = *(const s16x8*)qp;
        qh[1] = *(const s16x8*)(qp + 32);
        ql[0] = *(const s16x8*)qp2;
        ql[1] = *(const s16x8*)(qp2 + 32);
    }

    f32x4 racc[4];
    #pragma unroll
    for (int i = 0; i < 4; ++i) racc[i] = (f32x4){0.f, 0.f, 0.f, 0.f};

    // prologue prefetch of tile stLo
    s16x8 pk0, pk1, pv0, pv1;
    {
        const long ko = base + (long)(stLo * 64 + srow) * 64 + scol;
        pk0 = *(const s16x8*)(Kh_g + ko);
        pk1 = *(const s16x8*)(Kh_g + ko + 8);
        const long vo = base + (long)srow * 2048 + stLo * 64 + scol;
        pv0 = *(const s16x8*)(Vth_g + vo);
        pv1 = *(const s16x8*)(Vth_g + vo + 8);
    }

    for (int st = stLo; st <= qt; ++st) {
        const int s0 = st * 64;
        __syncthreads();
        *(s16x8*)&KhS[srow * 72 + scol]     = pk0;
        *(s16x8*)&KhS[srow * 72 + scol + 8] = pk1;
        *(s16x8*)&VhS[srow * 72 + scol]     = pv0;
        *(s16x8*)&VhS[srow * 72 + scol + 8] = pv1;
        __syncthreads();

        if (st < qt) {
            const long ko = base + (long)(s0 + 64 + srow) * 64 + scol;
            pk0 = *(const s16x8*)(Kh_g + ko);
            pk1 = *(const s16x8*)(Kh_g + ko + 8);
            const long vo = base + (long)srow * 2048 + s0 + 64 + scol;
            pv0 = *(const s16x8*)(Vth_g + vo);
            pv1 = *(const s16x8*)(Vth_g + vo + 8);
        }

        const float t0 = exp2f((float)(n - s0 - quad * 4) * l2g);

        #pragma unroll
        for (int sub = 0; sub < 4; ++sub) {
            const int ro = (sub * 16 + l15) * 72 + quad * 8;
            s16x8 kh0 = *(const s16x8*)&KhS[ro];
            s16x8 kh1 = *(const s16x8*)&KhS[ro + 32];
            f32x4 sacc = (f32x4){0.f, 0.f, 0.f, 0.f};
            sacc = __builtin_amdgcn_mfma_f32_16x16x32_bf16(kh0, qh[0], sacc, 0, 0, 0);
            sacc = __builtin_amdgcn_mfma_f32_16x16x32_bf16(kh1, qh[1], sacc, 0, 0, 0);
            sacc = __builtin_amdgcn_mfma_f32_16x16x32_bf16(kh0, ql[0], sacc, 0, 0, 0);
            sacc = __builtin_amdgcn_mfma_f32_16x16x32_bf16(kh1, ql[1], sacc, 0, 0, 0);

            const int sb = s0 + sub * 16 + quad * 4;
            s16x4 pkh;
            #pragma unroll
            for (int r = 0; r < 4; ++r) {
                const int s = sb + r;
                const float wgt = (n >= s) ? t0 * gneg[sub * 4 + r] : 0.0f;
                pkh[r] = f2bf(sacc[r] * wgt);
            }
            *(s16x4*)&PhS[(wv * 16 + l15) * 68 + sub * 16 + quad * 4] = pkh;
        }

        const int pro = (wv * 16 + l15) * 68 + quad * 8;
        s16x8 ph0 = *(const s16x8*)&PhS[pro];
        s16x8 ph1 = *(const s16x8*)&PhS[pro + 32];
        #pragma unroll
        for (int ds = 0; ds < 4; ++ds) {
            const int ro = (ds * 16 + l15) * 72 + quad * 8;
            s16x8 vh0 = *(const s16x8*)&VhS[ro];
            s16x8 vh1 = *(const s16x8*)&VhS[ro + 32];
            racc[ds] = __builtin_amdgcn_mfma_f32_16x16x32_bf16(ph0, vh0, racc[ds], 0, 0, 0);
            racc[ds] = __builtin_amdgcn_mfma_f32_16x16x32_bf16(ph1, vh1, racc[ds], 0, 0, 0);
        }
    }

    float mean[4], rstd[4];
    #pragma unroll
    for (int r = 0; r < 4; ++r) {
        float s = racc[0][r] + racc[1][r] + racc[2][r] + racc[3][r];
        s += __shfl_xor(s, 1); s += __shfl_xor(s, 2);
        s += __shfl_xor(s, 4); s += __shfl_xor(s, 8);
        mean[r] = s * (1.0f / 64.0f);
        float vs = 0.f;
        #pragma unroll
        for (int ds = 0; ds < 4; ++ds) {
            float d = racc[ds][r] - mean[r];
            vs += d * d;
        }
        vs += __shfl_xor(vs, 1); vs += __shfl_xor(vs, 2);
        vs += __shfl_xor(vs, 4); vs += __shfl_xor(vs, 8);
        rstd[r] = rsqrtf(vs * (1.0f / 64.0f) + 1e-6f);
    }

    __syncthreads();
    short* rgH = KhS + wv * 1152;
    #pragma unroll
    for (int ds = 0; ds < 4; ++ds) {
        #pragma unroll
        for (int r = 0; r < 4; ++r) {
            const int nn = n0 + wv * 16 + quad * 4 + r;
            const int d = ds * 16 + l15;
            const long gi = ((long)(b * 2048 + nn)) * 512 + h * 64 + d;
            float rg = (racc[ds][r] - mean[r]) * rstd[r] * G[gi];
            float prt = __shfl_xor(rg, 1);
            if (!(l15 & 1)) {
                const int o = (quad * 4 + r) * 72 + ds * 16 + l15;
                *(unsigned*)&rgH[o] = pack2(f2bf(rg), f2bf(prt));
            }
        }
    }
    #pragma unroll
    for (int p2 = 0; p2 < 2; ++p2) {
        const int row = p2 * 8 + (lane >> 3);
        const int ch = (lane & 7) * 8;
        s16x8 vh = *(const s16x8*)&rgH[row * 72 + ch];
        const int nn = n0 + wv * 16 + row;
        const long o = ((long)(b * 2048 + nn)) * 512 + h * 64 + ch;
        *(s16x8*)(RGh + o) = vh;
    }
}

// ---------------------------------------------------------------------------
// Output projection: out = RG(bf16) @ Wo^T + bo. 32x128 tile, waves 2x2.
// VGPR prefetch; fp32 output LDS-assembled.
// ---------------------------------------------------------------------------
__global__ __launch_bounds__(256) void projo_kernel(
    const short* __restrict__ RGh, const short* __restrict__ Woh_g,
    const float* __restrict__ bo, float* __restrict__ out)
{
    __shared__ __align__(16) char PB[23040];
    short* XhS = (short*)PB;            // 32*40
    short* WhS = XhS + 1280;            // 128*40
    short* WlS = XhS + 6400;

    const short* Wol_g = Woh_g + 262144;
    const int t = threadIdx.x, lane = t & 63, wv = t >> 6;
    const int wm = wv >> 1, wn = wv & 1;
    const int quad = lane >> 4, l15 = lane & 15;
    const int m0 = blockIdx.y * 32, n0 = blockIdx.x * 128;

    f32x4 acc[4];
    #pragma unroll
    for (int j = 0; j < 4; ++j) acc[j] = (f32x4){0.f, 0.f, 0.f, 0.f};

    const int xrow = t >> 3, xcol = (t & 7) * 4;
    const int wrow = t >> 1, wcol = (t & 1) * 16;
    const long xbase = (long)(m0 + xrow) * 512 + xcol;
    const long wbase = (long)(n0 + wrow) * 512 + wcol;

    s16x4 px;
    s16x8 pw0, pw1, pw2, pw3;
    px  = *(const s16x4*)(RGh + xbase);
    pw0 = *(const s16x8*)(Woh_g + wbase);
    pw1 = *(const s16x8*)(Woh_g + wbase + 8);
    pw2 = *(const s16x8*)(Wol_g + wbase);
    pw3 = *(const s16x8*)(Wol_g + wbase + 8);

    for (int k0 = 0; k0 < 512; k0 += 32) {
        __syncthreads();
        *(s16x4*)&XhS[xrow * 40 + xcol]     = px;
        *(s16x8*)&WhS[wrow * 40 + wcol]     = pw0;
        *(s16x8*)&WhS[wrow * 40 + wcol + 8] = pw1;
        *(s16x8*)&WlS[wrow * 40 + wcol]     = pw2;
        *(s16x8*)&WlS[wrow * 40 + wcol + 8] = pw3;
        __syncthreads();

        if (k0 + 32 < 512) {
            const long xo = xbase + k0 + 32;
            const long wo = wbase + k0 + 32;
            px  = *(const s16x4*)(RGh + xo);
            pw0 = *(const s16x8*)(Woh_g + wo);
            pw1 = *(const s16x8*)(Woh_g + wo + 8);
            pw2 = *(const s16x8*)(Wol_g + wo);
            pw3 = *(const s16x8*)(Wol_g + wo + 8);
        }

        s16x8 ah, bh[4], bl[4];
        {
            const int ro = (wm * 16 + l15) * 40 + quad * 8;
            ah = *(const s16x8*)&XhS[ro];
        }
        #pragma unroll
        for (int s = 0; s < 4; ++s) {
            const int ro = (wn * 64 + s * 16 + l15) * 40 + quad * 8;
            bh[s] = *(const s16x8*)&WhS[ro];
            bl[s] = *(const s16x8*)&WlS[ro];
        }
        #pragma unroll
        for (int j = 0; j < 4; ++j) {
            acc[j] = __builtin_amdgcn_mfma_f32_16x16x32_bf16(ah, bh[j], acc[j], 0, 0, 0);
            acc[j] = __builtin_amdgcn_mfma_f32_16x16x32_bf16(ah, bl[j], acc[j], 0, 0, 0);
        }
    }

    __syncthreads();
    float* T = (float*)PB + wv * 1152;   // 16 x 72 fp32
    #pragma unroll
    for (int ns = 0; ns < 4; ++ns) {
        const int col = n0 + wn * 64 + ns * 16 + l15;
        const float bvv = bo[col];
        #pragma unroll
        for (int r = 0; r < 4; ++r)
            T[(quad * 4 + r) * 72 + ns * 16 + l15] = acc[ns][r] + bvv;
    }
    #pragma unroll
    for (int it = 0; it < 2; ++it) {
        const int row = it * 8 + (lane >> 3);
        const int ch = (lane & 7) * 8;
        f32x4 a = *(const f32x4*)&T[row * 72 + ch];
        f32x4 c = *(const f32x4*)&T[row * 72 + ch + 4];
        const long o = (long)(m0 + wm * 16 + row) * 512 + n0 + wn * 64 + ch;
        *(f32x4*)(out + o) = a;
        *(f32x4*)(out + o + 4) = c;
    }
}

extern "C" void kernel_launch(void* const* d_in, const int* in_sizes, int n_in,
                              void* d_out, int out_size, void* d_ws, size_t ws_size,
                              hipStream_t stream) {
    const float* query = (const float*)d_in[0];
    const float* kin   = (const float*)d_in[1];
    const float* vin   = (const float*)d_in[2];
    const float* Wq = (const float*)d_in[3];
    const float* bq = (const float*)d_in[4];
    const float* Wk = (const float*)d_in[5];
    const float* bk = (const float*)d_in[6];
    const float* Wv = (const float*)d_in[7];
    const float* bv = (const float*)d_in[8];
    const float* Wg = (const float*)d_in[9];
    const float* bg = (const float*)d_in[10];
    const float* Wo = (const float*)d_in[11];
    const float* bo = (const float*)d_in[12];

    short* S = (short*)d_ws;
    const long NE = 2097152;             // 4096*512 elements
    short* WSp = S;                      // 5 MB
    short* Xsp = S + 2621440;            // 24 MB
    short* Qh  = Xsp + 12582912;
    short* Ql  = Qh + NE;
    short* Kh  = Ql + NE;
    short* Vth = Kh + NE;
    float* G   = (float*)(Vth + NE);     // NE floats
    short* RGh = (short*)(G + NE);

    presplit_kernel<<<1856, 256, 0, stream>>>(
        Wq, Wk, Wv, Wg, Wo, query, kin, vin, WSp, Xsp);
    projqkvg_kernel<<<dim3(4, 64, 4), 256, 0, stream>>>(
        Xsp, WSp, bq, bk, bv, bg, Qh, Ql, Kh, Vth, G);
    attn_kernel<<<dim3(32, 16), 256, 0, stream>>>(
        Qh, Ql, Kh, Vth, G, RGh);
    projo_kernel<<<dim3(4, 128), 256, 0, stream>>>(
        RGh, WSp + 4 * 524288, bo, (float*)d_out);
}